// Round 7
// baseline (554.449 us; speedup 1.0000x reference)
//
#include <hip/hip_runtime.h>
#include <math.h>

// ---------------------------------------------------------------------------
// LoRA T5 decoder layer on MI355X (gfx950).
// B=4, L=ENC=512, D=1024, H=16, HD=64, MLP=4096, R=32.
// R16->R17: k_prep transpose granularity fix. Three implementations all hit
// ~51us @2.0TB/s because 64x64 tiles touch DRAM at 256B (read) / 128B (write)
// granularity. New 128x128 tiles: 512B read segments, 256B write segments.
// Load: 4 k-rows x float4 per thread -> in-register 4x4 transpose -> ushort4
// (along-k) into LDS [n][k] bf16, stride 264B. Write: b64x2 row reads +
// uint4 global stores (4 x 256B contiguous rows per wave).
// ---------------------------------------------------------------------------

#define DEV __device__ __forceinline__

typedef __bf16 bf16x8 __attribute__((ext_vector_type(8)));
typedef float floatx4 __attribute__((ext_vector_type(4)));

typedef __attribute__((address_space(1))) void* gas_ptr;
typedef __attribute__((address_space(3))) void* las_ptr;

DEV unsigned short f2bf(float f) {
  union { float f; unsigned int u; } v; v.f = f;
  unsigned int r = v.u + 0x7fffu + ((v.u >> 16) & 1u);
  return (unsigned short)(r >> 16);
}
DEV float bf2f(unsigned short u) {
  union { unsigned int u; float f; } v; v.u = ((unsigned int)u) << 16;
  return v.f;
}

#define GLOAD_LDS16(g, l) __builtin_amdgcn_global_load_lds((gas_ptr)(g), (las_ptr)(l), 16, 0, 0)

// Swizzled staging, 128B rows: LDS physical chunk-col p of row r holds logical
// chunk (p ^ (r&7)). Lane p=(lane&7), r&7=(lane>>3)&7 -> load logical col
// (lane&7)^((lane>>3)&7). Same 128-B segments per wave => coalescing kept.
template<int NW>
DEV void stage_tile_sw(const char* gbase, char* lds, int nrows, int ldbytes, int wave, int lane) {
  int nchunks = nrows >> 3;
  int colb = (((lane & 7) ^ ((lane >> 3) & 7)) << 4);
  for (int c = wave; c < nchunks; c += NW) {
    int row = (c << 3) + (lane >> 3);
    GLOAD_LDS16(gbase + (size_t)row * ldbytes + colb, lds + (c << 10));
  }
}

// Swizzled staging, 256B rows (16 chunks/row): phys chunk p of row r holds
// logical (p ^ (r&7)). Here r&7 depends on c parity: r = (c<<2)+(lane>>4).
template<int NW>
DEV void stage_tile256_sw(const char* gbase, char* lds, int nrows, int ldbytes, int wave, int lane) {
  int nchunks = nrows >> 2;
  for (int c = wave; c < nchunks; c += NW) {
    int row = (c << 2) + (lane >> 4);
    int key = row & 7;
    int colb = ((lane & 15) ^ key) << 4;
    GLOAD_LDS16(gbase + (size_t)row * ldbytes + colb, lds + (c << 10));
  }
}

// ---------------- generic bf16 GEMM core (fp32 out), 128x128 tile ----------
// Swizzled LDS: fragment read col16 = ((kk>>3)+quad) ^ (l15&7).
template<int WM, int WN>
DEV void gemm_core(const unsigned short* A, const unsigned short* Bt, float* C,
                   int K, int lda, int ldb, int ldc, int m0, int n0,
                   char* ldsA, char* ldsB) {
  constexpr int NW = WM * WN;
  const int tid  = threadIdx.x;
  const int lane = tid & 63;
  const int wave = tid >> 6;
  const int wm   = wave % WM;
  const int wn   = wave / WM;
  const int quad = lane >> 4;
  const int l15  = lane & 15;
  const int key  = l15 & 7;

  floatx4 acc[4][4];
#pragma unroll
  for (int i = 0; i < 4; ++i)
#pragma unroll
    for (int j = 0; j < 4; ++j) acc[i][j] = (floatx4){0.f, 0.f, 0.f, 0.f};

  const char* gA = (const char*)(A + (size_t)m0 * lda);
  const char* gB = (const char*)(Bt + (size_t)n0 * ldb);

  for (int k0 = 0; k0 < K; k0 += 64) {
    stage_tile_sw<NW>(gA + (size_t)k0 * 2, ldsA, WM * 64, lda * 2, wave, lane);
    stage_tile_sw<NW>(gB + (size_t)k0 * 2, ldsB, WN * 64, ldb * 2, wave, lane);
    __syncthreads();
#pragma unroll
    for (int kk = 0; kk < 64; kk += 32) {
      bf16x8 af[4], bv[4];
      int off = (((kk >> 3) + quad) ^ key) << 4;
      const char* baseA = ldsA + (size_t)(wm * 64 + l15) * 128 + off;
      const char* baseB = ldsB + (size_t)(wn * 64 + l15) * 128 + off;
#pragma unroll
      for (int mi = 0; mi < 4; ++mi) af[mi] = *(const bf16x8*)(baseA + mi * 2048);
#pragma unroll
      for (int ni = 0; ni < 4; ++ni) bv[ni] = *(const bf16x8*)(baseB + ni * 2048);
#pragma unroll
      for (int mi = 0; mi < 4; ++mi)
#pragma unroll
        for (int ni = 0; ni < 4; ++ni)
          acc[mi][ni] = __builtin_amdgcn_mfma_f32_16x16x32_bf16(af[mi], bv[ni], acc[mi][ni], 0, 0, 0);
    }
    __syncthreads();
  }

#pragma unroll
  for (int mi = 0; mi < 4; ++mi) {
#pragma unroll
    for (int r = 0; r < 4; ++r) {
      int row = m0 + wm * 64 + mi * 16 + quad * 4 + r;
#pragma unroll
      for (int ni = 0; ni < 4; ++ni) {
        int col = n0 + wn * 64 + ni * 16 + l15;
        C[(size_t)row * ldc + col] = acc[mi][ni][r];
      }
    }
  }
}

__global__ __launch_bounds__(256) void k_gemm1s(const unsigned short* A, const unsigned short* Bt,
                                                float* Cpart, size_t pstride,
                                                int Kchunk, int lda, int ldb, int ldc) {
  __shared__ char lds[32768];
  int s = blockIdx.z;
  size_t koff = (size_t)s * Kchunk;
  gemm_core<2, 2>(A + koff, Bt + koff, Cpart + (size_t)s * pstride,
                  Kchunk, lda, ldb, ldc,
                  blockIdx.y * 128, blockIdx.x * 128, lds, lds + 16384);
}

// ---------------- K-extended GEMM: C = [A0|Aext] @ [B0|Bext(b)]^T ----------
struct GXSlice {
  const unsigned short* A0;
  const unsigned short* Aext;
  const unsigned short* B0;
  const unsigned short* Bext;
  float* C;
  size_t bextb;            // per-b element stride of Bext (= N*128)
  int ldc, nxa, it0, it1;
};
struct GX { GXSlice s[4]; };

__global__ __launch_bounds__(256) void k_gemmx(GX g) {
  __shared__ char lds[32768];
  char* ldsA = lds;
  char* ldsB = lds + 16384;
  GXSlice sl = g.s[blockIdx.z];
  if ((int)blockIdx.x >= sl.nxa) return;
  const int m0 = blockIdx.y * 128, n0 = blockIdx.x * 128;
  const int b = m0 >> 9;
  const int tid = threadIdx.x, lane = tid & 63, wave = tid >> 6;
  const int wm = wave & 1, wn = wave >> 1;
  const int quad = lane >> 4, l15 = lane & 15;
  const int key = l15 & 7;

  floatx4 acc[4][4];
#pragma unroll
  for (int i = 0; i < 4; ++i)
#pragma unroll
    for (int j = 0; j < 4; ++j) acc[i][j] = (floatx4){0.f, 0.f, 0.f, 0.f};

  for (int it = sl.it0; it < sl.it1; ++it) {
    if (it < 16) {
      stage_tile_sw<4>((const char*)sl.A0 + (size_t)m0 * 2048 + it * 128, ldsA, 128, 2048, wave, lane);
      stage_tile_sw<4>((const char*)sl.B0 + (size_t)n0 * 2048 + it * 128, ldsB, 128, 2048, wave, lane);
    } else {
      int eb = (it - 16) * 128;
      stage_tile_sw<4>((const char*)sl.Aext + (size_t)m0 * 256 + eb, ldsA, 128, 256, wave, lane);
      stage_tile_sw<4>((const char*)(sl.Bext + (size_t)b * sl.bextb) + (size_t)n0 * 256 + eb,
                       ldsB, 128, 256, wave, lane);
    }
    __syncthreads();
#pragma unroll
    for (int kk = 0; kk < 64; kk += 32) {
      bf16x8 af[4], bv[4];
      int off = (((kk >> 3) + quad) ^ key) << 4;
      const char* baseA = ldsA + (size_t)(wm * 64 + l15) * 128 + off;
      const char* baseB = ldsB + (size_t)(wn * 64 + l15) * 128 + off;
#pragma unroll
      for (int mi = 0; mi < 4; ++mi) af[mi] = *(const bf16x8*)(baseA + mi * 2048);
#pragma unroll
      for (int ni = 0; ni < 4; ++ni) bv[ni] = *(const bf16x8*)(baseB + ni * 2048);
#pragma unroll
      for (int mi = 0; mi < 4; ++mi)
#pragma unroll
        for (int ni = 0; ni < 4; ++ni)
          acc[mi][ni] = __builtin_amdgcn_mfma_f32_16x16x32_bf16(af[mi], bv[ni], acc[mi][ni], 0, 0, 0);
    }
    __syncthreads();
  }

#pragma unroll
  for (int mi = 0; mi < 4; ++mi) {
#pragma unroll
    for (int r = 0; r < 4; ++r) {
      int row = m0 + wm * 64 + mi * 16 + quad * 4 + r;
#pragma unroll
      for (int ni = 0; ni < 4; ++ni) {
        int col = n0 + wn * 64 + ni * 16 + l15;
        sl.C[(size_t)row * sl.ldc + col] = acc[mi][ni][r];
      }
    }
  }
}

// ---------------- fused QKV GEMM: bf16 epilogue + in-LDS V transpose ------
// C = [A0|Aext] @ [B0|Bext(b)]^T, K = 1024+128 in one pass (18 iters).
// Output sections (1024 cols each): row-major bf16, except section vsec
// which is V: each wave's 64x64 subtile spans one head h; transposed in a
// per-wave padded LDS buffer (64 rows x 136B) and stored coalesced to
// vdst[(b*16+h)*64 + d][512 k].
struct QKVSlice {
  const unsigned short* A0;
  const unsigned short* Aext;
  const unsigned short* B0;
  const unsigned short* Bext;
  unsigned short* sec0;
  unsigned short* sec1;
  unsigned short* sec2;
  size_t bextb;
  int vsec, nxa;
};
struct QKV2 { QKVSlice s[2]; };

__global__ __launch_bounds__(256) void k_gemmqkv(QKV2 g) {
  __shared__ char lds[34816];          // 32KB staging; reused: 4 x 8704B vbuf
  char* ldsA = lds;
  char* ldsB = lds + 16384;
  QKVSlice sl = g.s[blockIdx.z];
  if ((int)blockIdx.x >= sl.nxa) return;
  const int m0 = blockIdx.y * 128, n0 = blockIdx.x * 128;
  const int b = m0 >> 9;
  const int tid = threadIdx.x, lane = tid & 63, wave = tid >> 6;
  const int wm = wave & 1, wn = wave >> 1;
  const int quad = lane >> 4, l15 = lane & 15;
  const int key = l15 & 7;

  floatx4 acc[4][4];
#pragma unroll
  for (int i = 0; i < 4; ++i)
#pragma unroll
    for (int j = 0; j < 4; ++j) acc[i][j] = (floatx4){0.f, 0.f, 0.f, 0.f};

  for (int it = 0; it < 18; ++it) {
    if (it < 16) {
      stage_tile_sw<4>((const char*)sl.A0 + (size_t)m0 * 2048 + it * 128, ldsA, 128, 2048, wave, lane);
      stage_tile_sw<4>((const char*)sl.B0 + (size_t)n0 * 2048 + it * 128, ldsB, 128, 2048, wave, lane);
    } else {
      int eb = (it - 16) * 128;
      stage_tile_sw<4>((const char*)sl.Aext + (size_t)m0 * 256 + eb, ldsA, 128, 256, wave, lane);
      stage_tile_sw<4>((const char*)(sl.Bext + (size_t)b * sl.bextb) + (size_t)n0 * 256 + eb,
                       ldsB, 128, 256, wave, lane);
    }
    __syncthreads();
#pragma unroll
    for (int kk = 0; kk < 64; kk += 32) {
      bf16x8 af[4], bv[4];
      int off = (((kk >> 3) + quad) ^ key) << 4;
      const char* baseA = ldsA + (size_t)(wm * 64 + l15) * 128 + off;
      const char* baseB = ldsB + (size_t)(wn * 64 + l15) * 128 + off;
#pragma unroll
      for (int mi = 0; mi < 4; ++mi) af[mi] = *(const bf16x8*)(baseA + mi * 2048);
#pragma unroll
      for (int ni = 0; ni < 4; ++ni) bv[ni] = *(const bf16x8*)(baseB + ni * 2048);
#pragma unroll
      for (int mi = 0; mi < 4; ++mi)
#pragma unroll
        for (int ni = 0; ni < 4; ++ni)
          acc[mi][ni] = __builtin_amdgcn_mfma_f32_16x16x32_bf16(af[mi], bv[ni], acc[mi][ni], 0, 0, 0);
    }
    __syncthreads();
  }

  const int sec = n0 >> 10;
  const int nloc = n0 & 1023;
  if (sec != sl.vsec) {
    // row-major bf16 store (q or k section)
    unsigned short* dst = (sec == 0) ? sl.sec0 : sl.sec1;
#pragma unroll
    for (int mi = 0; mi < 4; ++mi)
#pragma unroll
      for (int r = 0; r < 4; ++r) {
        int row = m0 + wm * 64 + mi * 16 + quad * 4 + r;
        unsigned short* drow = dst + (size_t)row * 1024 + nloc + wn * 64;
#pragma unroll
        for (int ni = 0; ni < 4; ++ni)
          drow[ni * 16 + l15] = f2bf(acc[mi][ni][r]);
      }
  } else {
    // V section: per-wave 64x64 transpose via LDS (staging LDS is free here).
    unsigned short* vdstb = (sl.vsec == 1) ? sl.sec1 : sl.sec2;
    char* vbuf = lds + (size_t)(wm * 2 + wn) * 8704;   // [64 d][136B] (68 elem rows)
#pragma unroll
    for (int ni = 0; ni < 4; ++ni)
#pragma unroll
      for (int mi = 0; mi < 4; ++mi) {
        unsigned long long pk =
            (unsigned long long)f2bf(acc[mi][ni][0])
          | ((unsigned long long)f2bf(acc[mi][ni][1]) << 16)
          | ((unsigned long long)f2bf(acc[mi][ni][2]) << 32)
          | ((unsigned long long)f2bf(acc[mi][ni][3]) << 48);
        *(unsigned long long*)(vbuf + (size_t)(ni * 16 + l15) * 136 + (mi * 16 + quad * 4) * 2) = pk;
      }
    __syncthreads();
    int dbase = nloc + wn * 64;        // multiple of 64 -> one head per wave
    int h = dbase >> 6;
    int kb = (m0 & 511) + wm * 64;
    unsigned short* vdst = vdstb + (size_t)(b * 16 + h) * 64 * 512;
    int lh = lane >> 3, ll = lane & 7;
#pragma unroll
    for (int i = 0; i < 8; ++i) {
      int d = i * 8 + lh;
      const char* p = vbuf + (size_t)d * 136 + ll * 16;
      unsigned long long lo = *(const unsigned long long*)p;
      unsigned long long hi = *(const unsigned long long*)(p + 8);
      uint4 v;
      v.x = (unsigned)lo; v.y = (unsigned)(lo >> 32);
      v.z = (unsigned)hi; v.w = (unsigned)(hi >> 32);
      *(uint4*)(vdst + (size_t)d * 512 + kb + ll * 8) = v;
    }
  }
}

// ---------------- flash attention (XOR-swizzled LDS) ----------------------
// All tiles: phys 16B chunk = logical chunk ^ (row&7). ldsQ/ldsK rows are
// 128B (8 chunks), ldsV/ldsP rows are 256B (16 chunks; 3-bit key keeps bit3).
template<bool CAUSAL, bool QSUM>
__global__ __launch_bounds__(256) void k_flash(const unsigned short* qmat, const float* qparts,
                                               const unsigned short* kmat, const unsigned short* vt,
                                               const float* rb, unsigned short* ctxb) {
  __shared__ char ldsQ[8192];    // [64 q][64 d]
  __shared__ char ldsK[16384];   // [128 k][64 d]
  __shared__ char ldsV[16384];   // [64 d][128 k]
  __shared__ char ldsP[16384];   // [64 q][128 k]
  __shared__ float lrb[512];

  const size_t PART = (size_t)2048 * 1024;
  const int z = blockIdx.y, b = z >> 4, h = z & 15;
  const int q0 = blockIdx.x * 64;
  const int tid = threadIdx.x, lane = tid & 63, wave = tid >> 6;
  const int quad = lane >> 4, l15 = lane & 15;
  const int key = l15 & 7;

  const unsigned short* K = kmat + (size_t)b * 512 * 1024 + h * 64;
  const unsigned short* V = vt + (size_t)z * 64 * 512;

  if (QSUM) {
#pragma unroll
    for (int rr = 0; rr < 4; ++rr) {
      int row = rr * 16 + (tid >> 4);
      int c4 = tid & 15;
      const float* src = qparts + (size_t)(q0 + row) * 1024 + h * 64 + c4 * 4;
      float4 s0 = *(const float4*)src;
      float4 s1 = *(const float4*)(src + PART);
      float4 s2 = *(const float4*)(src + 2 * PART);
      float4 s3 = *(const float4*)(src + 3 * PART);
      ushort4 o;
      o.x = f2bf(s0.x + s1.x + s2.x + s3.x);
      o.y = f2bf(s0.y + s1.y + s2.y + s3.y);
      o.z = f2bf(s0.z + s1.z + s2.z + s3.z);
      o.w = f2bf(s0.w + s1.w + s2.w + s3.w);
      // 8B granule: logical chunk = c4>>1, half = c4&1; swizzle the chunk.
      int qoff = (((c4 >> 1) ^ (row & 7)) << 4) | ((c4 & 1) << 3);
      *(ushort4*)(ldsQ + (size_t)row * 128 + qoff) = o;
    }
  } else {
    const unsigned short* Q = qmat + (size_t)b * 512 * 1024 + h * 64;
    stage_tile_sw<4>((const char*)(Q + (size_t)q0 * 1024), ldsQ, 64, 2048, wave, lane);
  }
  if (CAUSAL)
    for (int i = tid; i < 512; i += 256) lrb[i] = rb[h * 512 + i];

  float m_run[4], l_run[4];
  floatx4 oacc[4];
#pragma unroll
  for (int r = 0; r < 4; ++r) { m_run[r] = -1e30f; l_run[r] = 0.f; }
#pragma unroll
  for (int ni = 0; ni < 4; ++ni) oacc[ni] = (floatx4){0.f, 0.f, 0.f, 0.f};

  const int ktend = CAUSAL ? (blockIdx.x / 2 + 1) : 4;
  for (int kt = 0; kt < ktend; ++kt) {
    __syncthreads();
    stage_tile_sw<4>((const char*)(K + (size_t)kt * 128 * 1024), ldsK, 128, 2048, wave, lane);
    stage_tile256_sw<4>((const char*)(V + kt * 128), ldsV, 64, 1024, wave, lane);
    __syncthreads();

    floatx4 sacc[8];
#pragma unroll
    for (int ct = 0; ct < 8; ++ct) sacc[ct] = (floatx4){0.f, 0.f, 0.f, 0.f};
    const size_t qrow = (size_t)(wave * 16 + l15) * 128;
#pragma unroll
    for (int kd = 0; kd < 2; ++kd) {
      int offq = ((quad + kd * 4) ^ key) << 4;
      bf16x8 af = *(const bf16x8*)(ldsQ + qrow + offq);
#pragma unroll
      for (int ct = 0; ct < 8; ++ct) {
        bf16x8 bfv = *(const bf16x8*)(ldsK + (size_t)(ct * 16 + l15) * 128 + offq);
        sacc[ct] = __builtin_amdgcn_mfma_f32_16x16x32_bf16(af, bfv, sacc[ct], 0, 0, 0);
      }
    }

    float sv[8][4];
#pragma unroll
    for (int ct = 0; ct < 8; ++ct)
#pragma unroll
      for (int r = 0; r < 4; ++r) {
        float v = sacc[ct][r] * 0.125f;
        if (CAUSAL) {
          int qq = q0 + wave * 16 + quad * 4 + r;
          int kk = kt * 128 + ct * 16 + l15;
          v = (kk <= qq) ? v + lrb[qq - kk] : -1e30f;
        }
        sv[ct][r] = v;
      }

    float mx[4];
#pragma unroll
    for (int r = 0; r < 4; ++r) {
      mx[r] = sv[0][r];
#pragma unroll
      for (int ct = 1; ct < 8; ++ct) mx[r] = fmaxf(mx[r], sv[ct][r]);
    }
#pragma unroll
    for (int o = 1; o < 16; o <<= 1)
#pragma unroll
      for (int r = 0; r < 4; ++r) mx[r] = fmaxf(mx[r], __shfl_xor(mx[r], o));

    float alpha[4], rs[4];
#pragma unroll
    for (int r = 0; r < 4; ++r) {
      float mn = fmaxf(m_run[r], mx[r]);
      alpha[r] = __expf(m_run[r] - mn);
      m_run[r] = mn;
      rs[r] = 0.f;
    }
#pragma unroll
    for (int ct = 0; ct < 8; ++ct)
#pragma unroll
      for (int r = 0; r < 4; ++r) {
        float p = __expf(sv[ct][r] - m_run[r]);
        sv[ct][r] = p;
        rs[r] += p;
      }
#pragma unroll
    for (int o = 1; o < 16; o <<= 1)
#pragma unroll
      for (int r = 0; r < 4; ++r) rs[r] += __shfl_xor(rs[r], o);
#pragma unroll
    for (int r = 0; r < 4; ++r) l_run[r] = l_run[r] * alpha[r] + rs[r];
#pragma unroll
    for (int ni = 0; ni < 4; ++ni)
#pragma unroll
      for (int r = 0; r < 4; ++r) oacc[ni][r] *= alpha[r];

#pragma unroll
    for (int ct = 0; ct < 8; ++ct)
#pragma unroll
      for (int r = 0; r < 4; ++r) {
        int prow_w = wave * 16 + quad * 4 + r;
        int kidx = ct * 16 + l15;
        int pb = (((kidx >> 3) ^ (prow_w & 7)) << 4) | ((kidx & 7) << 1);
        *(unsigned short*)(ldsP + (size_t)prow_w * 256 + pb) = f2bf(sv[ct][r]);
      }
    __syncthreads();

    const size_t prow = (size_t)(wave * 16 + l15) * 256;
#pragma unroll
    for (int kk = 0; kk < 4; ++kk) {
      int offp = ((quad + kk * 4) ^ key) << 4;
      bf16x8 pf = *(const bf16x8*)(ldsP + prow + offp);
#pragma unroll
      for (int ni = 0; ni < 4; ++ni) {
        bf16x8 vf8 = *(const bf16x8*)(ldsV + (size_t)(ni * 16 + l15) * 256 + offp);
        oacc[ni] = __builtin_amdgcn_mfma_f32_16x16x32_bf16(pf, vf8, oacc[ni], 0, 0, 0);
      }
    }
  }

#pragma unroll
  for (int r = 0; r < 4; ++r) {
    int q = q0 + wave * 16 + quad * 4 + r;
    float inv = 1.0f / l_run[r];
    unsigned short* dst = ctxb + ((size_t)b * 512 + q) * 1024 + h * 64;
#pragma unroll
    for (int ni = 0; ni < 4; ++ni)
      dst[ni * 16 + l15] = f2bf(oacc[ni][r] * inv);
  }
}

// ---------------- fused MLP (swizzled LDS) ----------------
__global__ __launch_bounds__(512) void k_mlp(const unsigned short* A, const unsigned short* Wc,
                                             unsigned short* hbf) {
  __shared__ char lds[49152];
  char* ldsA = lds;
  char* ldsB = lds + 16384;
  const int m0 = blockIdx.y * 128;
  const int n0 = blockIdx.x * 128;
  const int tid = threadIdx.x, lane = tid & 63, wave = tid >> 6;
  const int half = wave >> 2, wl = wave & 3;
  const int wm = wl & 1, wn = wl >> 1;
  const int quad = lane >> 4, l15 = lane & 15;
  const int key = l15 & 7;

  floatx4 acc[4][4];
#pragma unroll
  for (int i = 0; i < 4; ++i)
#pragma unroll
    for (int j = 0; j < 4; ++j) acc[i][j] = (floatx4){0.f, 0.f, 0.f, 0.f};

  const char* gA = (const char*)(A + (size_t)m0 * 1024);
  const char* gB = (const char*)(Wc + (size_t)blockIdx.x * 256 * 1024);

  for (int k0 = 0; k0 < 1024; k0 += 64) {
    stage_tile_sw<8>(gA + (size_t)k0 * 2, ldsA, 128, 2048, wave, lane);
    stage_tile_sw<8>(gB + (size_t)k0 * 2, ldsB, 256, 2048, wave, lane);
    __syncthreads();
#pragma unroll
    for (int kk = 0; kk < 64; kk += 32) {
      bf16x8 af[4], bv[4];
      int off = (((kk >> 3) + quad) ^ key) << 4;
      const char* baseA = ldsA + (size_t)(wm * 64 + l15) * 128 + off;
      const char* baseB = ldsB + (size_t)(half * 128 + wn * 64 + l15) * 128 + off;
#pragma unroll
      for (int mi = 0; mi < 4; ++mi) af[mi] = *(const bf16x8*)(baseA + mi * 2048);
#pragma unroll
      for (int ni = 0; ni < 4; ++ni) bv[ni] = *(const bf16x8*)(baseB + ni * 2048);
#pragma unroll
      for (int mi = 0; mi < 4; ++mi)
#pragma unroll
        for (int ni = 0; ni < 4; ++ni)
          acc[mi][ni] = __builtin_amdgcn_mfma_f32_16x16x32_bf16(af[mi], bv[ni], acc[mi][ni], 0, 0, 0);
    }
    __syncthreads();
  }

  if (half == 1) {
#pragma unroll
    for (int mi = 0; mi < 4; ++mi)
#pragma unroll
      for (int r = 0; r < 4; ++r) {
        int row = wm * 64 + mi * 16 + quad * 4 + r;
#pragma unroll
        for (int ni = 0; ni < 4; ++ni) {
          int col = wn * 64 + ni * 16 + l15;
          *(unsigned short*)(ldsB + (size_t)row * 256 + col * 2) = f2bf(acc[mi][ni][r]);
        }
      }
  }
  __syncthreads();
  if (half == 0) {
#pragma unroll
    for (int mi = 0; mi < 4; ++mi)
#pragma unroll
      for (int r = 0; r < 4; ++r) {
        int row = wm * 64 + mi * 16 + quad * 4 + r;
#pragma unroll
        for (int ni = 0; ni < 4; ++ni) {
          int col = wn * 64 + ni * 16 + l15;
          float h1 = bf2f(*(const unsigned short*)(ldsB + (size_t)row * 256 + col * 2));
          float g = acc[mi][ni][r];
          float v = 0.5f * g * (1.0f + erff(g * 0.70710678f)) * h1;
          hbf[(size_t)(m0 + row) * 4096 + n0 + col] = f2bf(v);
        }
      }
  }
}

// ---------------- prep: fast transpose + encbf + relbias + bmext ----------
// 128x128 transpose tiles: 512B read / 256B write DRAM granularity.
// LDS tile [n][k] bf16, row stride 264B; in-register 4x4 transpose on load.
struct PrepArgs {
  const float* src[11];
  unsigned short* dst[11];
  int K[11], N[11], mode[11];
  int tstart[12];
  const float* encoded;
  unsigned short* encbf;
  const float* table;
  float* rb;
  unsigned short* bmdst[5];
  const float* bmsrc[5][3];
  int bmnrg[5];
  int bmstart[6];
  int nwt, nf2bf, nbm;
};
__global__ __launch_bounds__(256, 2) void k_prep(PrepArgs a) {
  __shared__ char ldsT[33792];   // 128 n-rows x 264B (128 bf16 + pad)
  int bid = blockIdx.x;
  int t = threadIdx.x;
  if (bid < a.nwt) {
    int z = 0;
    while (z < 10 && bid >= a.tstart[z + 1]) ++z;
    int tile = bid - a.tstart[z];
    int N = a.N[z], K = a.K[z], mode = a.mode[z];
    int ntn = N >> 7;
    int tn = tile % ntn, tk = tile / ntn;
    const float* src = a.src[z] + (size_t)(tk * 128) * N + tn * 128;
    // load 128x128 fp32 (512B row segments), 4x4 reg transpose, LDS [n][k]
#pragma unroll
    for (int i = 0; i < 4; ++i) {
      int c = i * 256 + t;                // 0..1023
      int k4 = c >> 5;                    // 0..31 (k0 = k4*4)
      int c4 = c & 31;                    // col4 (n0 = c4*4)
      const float* p = src + (size_t)(k4 * 4) * N + c4 * 4;
      float4 v0 = *(const float4*)(p);
      float4 v1 = *(const float4*)(p + N);
      float4 v2 = *(const float4*)(p + 2 * (size_t)N);
      float4 v3 = *(const float4*)(p + 3 * (size_t)N);
      char* base = ldsT + (size_t)(c4 * 4) * 264 + k4 * 8;
      ushort4 o;
      o.x = f2bf(v0.x); o.y = f2bf(v1.x); o.z = f2bf(v2.x); o.w = f2bf(v3.x);
      *(ushort4*)(base) = o;
      o.x = f2bf(v0.y); o.y = f2bf(v1.y); o.z = f2bf(v2.y); o.w = f2bf(v3.y);
      *(ushort4*)(base + 264) = o;
      o.x = f2bf(v0.z); o.y = f2bf(v1.z); o.z = f2bf(v2.z); o.w = f2bf(v3.z);
      *(ushort4*)(base + 528) = o;
      o.x = f2bf(v0.w); o.y = f2bf(v1.w); o.z = f2bf(v2.w); o.w = f2bf(v3.w);
      *(ushort4*)(base + 792) = o;
    }
    __syncthreads();
    {
      int g2 = t >> 4, j = t & 15;        // 16 row-groups x 16 chunks
#pragma unroll
      for (int rr = 0; rr < 8; ++rr) {
        int nl = rr * 16 + g2;
        int n = tn * 128 + nl;
        int orow = (mode == 0) ? n : ((n >> 7) * 256 + ((mode == 2) ? 128 : 0) + (n & 127));
        const char* p = ldsT + (size_t)nl * 264 + j * 16;
        unsigned long long lo = *(const unsigned long long*)p;
        unsigned long long hi = *(const unsigned long long*)(p + 8);
        uint4 v;
        v.x = (unsigned)lo; v.y = (unsigned)(lo >> 32);
        v.z = (unsigned)hi; v.w = (unsigned)(hi >> 32);
        *(uint4*)(a.dst[z] + (size_t)orow * K + tk * 128 + j * 8) = v;
      }
    }
    return;
  }
  bid -= a.nwt;
  if (bid < a.nf2bf) {
    // 256 blocks x 8 batched float4 per thread (2M floats total).
    const float4* src = (const float4*)a.encoded;
    ushort4* dst = (ushort4*)a.encbf;
    int base = bid * 2048 + t;
    float4 v[8];
#pragma unroll
    for (int i = 0; i < 8; ++i) v[i] = src[base + i * 256];
#pragma unroll
    for (int i = 0; i < 8; ++i) {
      ushort4 o;
      o.x = f2bf(v[i].x); o.y = f2bf(v[i].y); o.z = f2bf(v[i].z); o.w = f2bf(v[i].w);
      dst[base + i * 256] = o;
    }
    return;
  }
  bid -= a.nf2bf;
  if (bid < 32) {
    int i = bid * 256 + t;
    if (i < 16 * 512) {
      int h = i >> 9, d = i & 511;
      int bucket;
      if (d < 16) bucket = d;
      else {
        int lb = 16 + (int)(logf((float)d / 16.0f) / logf(8.0f) * 16.0f);
        bucket = lb < 31 ? lb : 31;
      }
      a.rb[i] = a.table[bucket * 16 + h];
    }
    return;
  }
  bid -= 32;
  {
    // bmext fill: Bext[b][row=n0+n][c] = (c>>5==sec) ? b_sec[b][c&31][(n0&1023)+n] : 0
    int m = 0;
    while (m < 4 && bid >= a.bmstart[m + 1]) ++m;
    int idx = bid - a.bmstart[m];
    int nrg = a.bmnrg[m];
    int b = idx / nrg, rg = idx % nrg;
    int n0 = rg * 128;
    int sec = n0 >> 10;
    const float* src = a.bmsrc[m][sec] + (size_t)b * 65536;
    unsigned short* dst = a.bmdst[m] + ((size_t)b * nrg * 128 + n0) * 128;
    int n = t & 127, coff = (t >> 7) * 64;
    int ncol = (n0 & 1023) + n;
    unsigned short* drow = dst + (size_t)n * 128 + coff;
    for (int cg = 0; cg < 16; cg += 8) {
      float vv[8][4];
#pragma unroll
      for (int cc = 0; cc < 8; ++cc)
#pragma unroll
        for (int e = 0; e < 4; ++e) {
          int c = coff + (cg + cc) * 4 + e;
          vv[cc][e] = ((c >> 5) == sec) ? src[(size_t)(c & 31) * 1024 + ncol] : 0.f;
        }
#pragma unroll
      for (int cc = 0; cc < 8; ++cc) {
        ushort4 o;
        o.x = f2bf(vv[cc][0]); o.y = f2bf(vv[cc][1]);
        o.z = f2bf(vv[cc][2]); o.w = f2bf(vv[cc][3]);
        *(ushort4*)(drow + (cg + cc) * 4) = o;
      }
    }
  }
}

// ---------------- cross-KV lows from fp32 encoded (own 48KB kernel) -------
__global__ __launch_bounds__(256) void k_lowc(const float* encoded, const float* a0g,
                                              const float* a1g, unsigned short* lowc) {
  __shared__ float rowsF[8 * 1024];            // 32 KB
  __shared__ float pacc[2 * 8 * 8 * 32];       // 16 KB
  int t = threadIdx.x;
  int row0 = blockIdx.x * 8;
  int b = row0 >> 9;
  for (int j = 0; j < 8; ++j)
    ((float4*)(rowsF + j * 1024))[t] = ((const float4*)(encoded + (size_t)(row0 + j) * 1024))[t];
  __syncthreads();
  int r = t & 31, g = t >> 5;
  float acc[2][8];
#pragma unroll
  for (int p = 0; p < 2; ++p)
#pragma unroll
    for (int j = 0; j < 8; ++j) acc[p][j] = 0.f;
  const float* a0 = a0g + (size_t)b * 65536;
  const float* a1 = a1g + (size_t)b * 65536;
  for (int i = 0; i < 128; ++i) {
    int k = g * 128 + i;
    float ak = a0[(size_t)k * 32 + r];
    float av = a1[(size_t)k * 32 + r];
#pragma unroll
    for (int j = 0; j < 8; ++j) {
      float x = rowsF[j * 1024 + k];
      acc[0][j] += x * ak;
      acc[1][j] += x * av;
    }
  }
#pragma unroll
  for (int p = 0; p < 2; ++p)
#pragma unroll
    for (int j = 0; j < 8; ++j)
      pacc[((p * 8 + j) * 8 + g) * 32 + r] = acc[p][j];
  __syncthreads();
  for (int j = 0; j < 8; ++j) {
    if (t < 64) {
      int p = t >> 5, r2 = t & 31;
      float s = 0.f;
      for (int gg = 0; gg < 8; ++gg) s += pacc[((p * 8 + j) * 8 + gg) * 32 + r2];
      lowc[(size_t)(row0 + j) * 128 + p * 32 + r2] = f2bf(s);
    } else if (t < 128) {
      lowc[(size_t)(row0 + j) * 128 + t] = 0;
    }
  }
}

// ---------------- k_start: rmsnorm + self q/k/v lows ----------------------
__global__ __launch_bounds__(256) void k_start(const float* x, const float* sc,
                                               const float* qa, const float* ka, const float* va,
                                               unsigned short* xn, unsigned short* lowext) {
  __shared__ unsigned short lrows[8][1024];   // 16 KB
  __shared__ float pacc[3 * 8 * 8 * 32];      // 24 KB
  __shared__ float red[4];
  int t = threadIdx.x;
  int row0 = blockIdx.x * 8;
  int b = row0 >> 9;
  float4 s4 = ((const float4*)sc)[t];
  for (int j = 0; j < 8; ++j) {
    int row = row0 + j;
    float4 v = ((const float4*)(x + (size_t)row * 1024))[t];
    float ss = v.x * v.x + v.y * v.y + v.z * v.z + v.w * v.w;
    for (int o = 32; o; o >>= 1) ss += __shfl_down(ss, o);
    if ((t & 63) == 0) red[t >> 6] = ss;
    __syncthreads();
    float tot = red[0] + red[1] + red[2] + red[3];
    float rs = rsqrtf(tot * (1.0f / 1024.0f) + 1e-6f);
    ushort4 o;
    o.x = f2bf(v.x * rs * s4.x); o.y = f2bf(v.y * rs * s4.y);
    o.z = f2bf(v.z * rs * s4.z); o.w = f2bf(v.w * rs * s4.w);
    ((ushort4*)(xn + (size_t)row * 1024))[t] = o;
    *(ushort4*)(&lrows[j][t * 4]) = o;
    __syncthreads();
  }
  int r = t & 31, g = t >> 5;
  float acc[3][8];
#pragma unroll
  for (int p = 0; p < 3; ++p)
#pragma unroll
    for (int j = 0; j < 8; ++j) acc[p][j] = 0.f;
  const float* aq = qa + (size_t)b * 65536;
  const float* ak = ka + (size_t)b * 65536;
  const float* av = va + (size_t)b * 65536;
  for (int i = 0; i < 128; ++i) {
    int k = g * 128 + i;
    float a0 = aq[(size_t)k * 32 + r];
    float a1 = ak[(size_t)k * 32 + r];
    float a2 = av[(size_t)k * 32 + r];
#pragma unroll
    for (int j = 0; j < 8; ++j) {
      float xv = bf2f(lrows[j][k]);
      acc[0][j] += xv * a0;
      acc[1][j] += xv * a1;
      acc[2][j] += xv * a2;
    }
  }
#pragma unroll
  for (int p = 0; p < 3; ++p)
#pragma unroll
    for (int j = 0; j < 8; ++j)
      pacc[((p * 8 + j) * 8 + g) * 32 + r] = acc[p][j];
  __syncthreads();
  for (int j = 0; j < 8; ++j) {
    if (t < 96) {
      int p = t >> 5, r2 = t & 31;
      float s = 0.f;
      for (int gg = 0; gg < 8; ++gg) s += pacc[((p * 8 + j) * 8 + gg) * 32 + r2];
      lowext[(size_t)(row0 + j) * 128 + p * 32 + r2] = f2bf(s);
    } else if (t < 128) {
      lowext[(size_t)(row0 + j) * 128 + t] = 0;
    }
  }
}

// ---------------- k_addbrms: 4-partial sum + resid + rms (+ next low) -----
template<bool LOW>
__global__ __launch_bounds__(256) void k_addbrms(const float* parts, const float* resid,
                                                 const float* sc, float* resout,
                                                 unsigned short* xn,
                                                 const float* aP, unsigned short* lowext) {
  __shared__ unsigned short lrows[8][1024];
  __shared__ float pacc[8 * 8 * 32];
  __shared__ float red[4];
  const size_t PART = (size_t)2048 * 1024;
  int t = threadIdx.x;
  int row0 = blockIdx.x * 8;
  int b = row0 >> 9;
  float4 s4 = ((const float4*)sc)[t];
  for (int j = 0; j < 8; ++j) {
    int row = row0 + j;
    const float* p0 = parts + (size_t)row * 1024;
    float4 v = ((const float4*)p0)[t];
    float4 v1 = ((const float4*)(p0 + PART))[t];
    float4 v2 = ((const float4*)(p0 + 2 * PART))[t];
    float4 v3 = ((const float4*)(p0 + 3 * PART))[t];
    float4 rv = ((const float4*)(resid + (size_t)row * 1024))[t];
    float4 s;
    s.x = v.x + v1.x + v2.x + v3.x + rv.x;
    s.y = v.y + v1.y + v2.y + v3.y + rv.y;
    s.z = v.z + v1.z + v2.z + v3.z + rv.z;
    s.w = v.w + v1.w + v2.w + v3.w + rv.w;
    ((float4*)(resout + (size_t)row * 1024))[t] = s;
    float ss = s.x * s.x + s.y * s.y + s.z * s.z + s.w * s.w;
    for (int o = 32; o; o >>= 1) ss += __shfl_down(ss, o);
    if ((t & 63) == 0) red[t >> 6] = ss;
    __syncthreads();
    float tot = red[0] + red[1] + red[2] + red[3];
    float rs = rsqrtf(tot * (1.0f / 1024.0f) + 1e-6f);
    ushort4 o;
    o.x = f2bf(s.x * rs * s4.x); o.y = f2bf(s.y * rs * s4.y);
    o.z = f2bf(s.z * rs * s4.z); o.w = f2bf(s.w * rs * s4.w);
    ((ushort4*)(xn + (size_t)row * 1024))[t] = o;
    if (LOW) *(ushort4*)(&lrows[j][t * 4]) = o;
    __syncthreads();
  }
  if (LOW) {
    int r = t & 31, g = t >> 5;
    float acc[8];
#pragma unroll
    for (int j = 0; j < 8; ++j) acc[j] = 0.f;
    const float* ap = aP + (size_t)b * 65536;
    for (int i = 0; i < 128; ++i) {
      int k = g * 128 + i;
      float a0 = ap[(size_t)k * 32 + r];
#pragma unroll
      for (int j = 0; j < 8; ++j) acc[j] += bf2f(lrows[j][k]) * a0;
    }
#pragma unroll
    for (int j = 0; j < 8; ++j) pacc[(j * 8 + g) * 32 + r] = acc[j];
    __syncthreads();
    for (int j = 0; j < 8; ++j) {
      if (t < 32) {
        float s = 0.f;
        for (int gg = 0; gg < 8; ++gg) s += pacc[(j * 8 + gg) * 32 + t];
        lowext[(size_t)(row0 + j) * 128 + t] = f2bf(s);
      } else if (t < 128) {
        lowext[(size_t)(row0 + j) * 128 + t] = 0;
      }
    }
  }
}

// ---------------- low for out-proj (ctx bf16 -> lowext bf16) --------------
__global__ __launch_bounds__(256) void k_lowbf(const unsigned short* x, const float* a,
                                               unsigned short* lowext) {
  int row0 = blockIdx.x * 8;
  int b = row0 >> 9;
  int t = threadIdx.x, r = t & 31, j = t >> 5;
  int row = row0 + j;
  const bf16x8* xv = (const bf16x8*)(x + (size_t)row * 1024);
  const float* ap = a + (size_t)b * 65536;
  float s = 0.f;
  for (int kb = 0; kb < 128; ++kb) {
    bf16x8 v = xv[kb];
#pragma unroll
    for (int u = 0; u < 8; ++u)
      s += (float)v[u] * ap[(size_t)(kb * 8 + u) * 32 + r];
  }
  lowext[(size_t)row * 128 + r] = f2bf(s);
  lowext[(size_t)row * 128 + 32 + r] = 0;
  lowext[(size_t)row * 128 + 64 + r] = 0;
  lowext[(size_t)row * 128 + 96 + r] = 0;
}

// ---------------- final sum ----------------
__global__ void k_sum4(const float* p, size_t pstride, const float* resid, float* out) {
  int i = blockIdx.x * 256 + threadIdx.x;
  float4 a = ((const float4*)p)[i];
  float4 b = ((const float4*)(p + pstride))[i];
  float4 c = ((const float4*)(p + 2 * pstride))[i];
  float4 d = ((const float4*)(p + 3 * pstride))[i];
  float4 r = ((const float4*)resid)[i];
  float4 o;
  o.x = a.x + b.x + c.x + d.x + r.x;
  o.y = a.y + b.y + c.y + d.y + r.y;
  o.z = a.z + b.z + c.z + d.z + r.z;
  o.w = a.w + b.w + c.w + d.w + r.w;
  ((float4*)out)[i] = o;
}

// ---------------------------------------------------------------------------

extern "C" void kernel_launch(void* const* d_in, const int* in_sizes, int n_in,
                              void* d_out, int out_size, void* d_ws, size_t ws_size,
                              hipStream_t stream) {
  const float* f_inputs  = (const float*)d_in[0];
  const float* f_encoded = (const float*)d_in[1];
  const float* f_qa = (const float*)d_in[2];
  const float* f_qb = (const float*)d_in[3];
  const float* f_ka = (const float*)d_in[4];
  const float* f_kb = (const float*)d_in[5];
  const float* f_va = (const float*)d_in[6];
  const float* f_vb = (const float*)d_in[7];
  const float* f_oa = (const float*)d_in[8];
  const float* f_ob = (const float*)d_in[9];
  const float* f_table = (const float*)d_in[10];
  const float* f_ln1 = (const float*)d_in[11];
  const float* f_ln2 = (const float*)d_in[12];
  const float* f_ln3 = (const float*)d_in[13];
  const float* f_W[8] = { (const float*)d_in[14], (const float*)d_in[15],
                          (const float*)d_in[16], (const float*)d_in[17],
                          (const float*)d_in[18], (const float*)d_in[19],
                          (const float*)d_in[20], (const float*)d_in[21] };
  const float* f_wi0 = (const float*)d_in[22];
  const float* f_wi1 = (const float*)d_in[23];
  const float* f_wo  = (const float*)d_in[24];

  const size_t SEL1 = 32768;
  const size_t PART = (size_t)2048 * 1024;

  char* w = (char*)d_ws;
  size_t off = 0;
  auto alloc = [&](size_t bytes) -> char* {
    off = (off + 255) & ~(size_t)255;
    char* p = w + off;
    off += bytes;
    return p;
  };
  unsigned short* wt  = (unsigned short*)alloc((size_t)8192 * 1024 * 2); // q,k,v,o,cq,ck,cv,co
  unsigned short* wc  = (unsigned short*)alloc((size_t)8192 * 1024 * 2); // interleaved wi0/wi1
  unsigned short* wot = (unsigned short*)alloc((size_t)1024 * 4096 * 2);
  unsigned short* encbf = (unsigned short*)alloc(2048 * 1024 * 2);
  float* rb = (float*)alloc(16 * 512 * 4);
  unsigned short* xn  = (unsigned short*)alloc(2048 * 1024 * 2);
  unsigned short* qbf = (unsigned short*)alloc(2048 * 1024 * 2);
  unsigned short* kbf = (unsigned short*)alloc(2048 * 1024 * 2);
  unsigned short* vtb = (unsigned short*)alloc((size_t)64 * 64 * 512 * 2);
  unsigned short* kbf2 = (unsigned short*)alloc(2048 * 1024 * 2);
  unsigned short* vtb2 = (unsigned short*)alloc((size_t)64 * 64 * 512 * 2);
  unsigned short* lowext_s = (unsigned short*)alloc(2048 * 128 * 2);
  unsigned short* lowext_c = (unsigned short*)alloc(2048 * 128 * 2);
  unsigned short* lowext_q = (unsigned short*)alloc(2048 * 128 * 2);
  unsigned short* lowext_o = (unsigned short*)alloc(2048 * 128 * 2);
  unsigned short* bmext_s  = (unsigned short*)alloc((size_t)4 * 3072 * 128 * 2);
  unsigned short* bmext_c  = (unsigned short*)alloc((size_t)4 * 2048 * 128 * 2);
  unsigned short* bmext_q  = (unsigned short*)alloc((size_t)4 * 1024 * 128 * 2);
  unsigned short* bmext_o  = (unsigned short*)alloc((size_t)4 * 1024 * 128 * 2);
  unsigned short* bmext_o2 = (unsigned short*)alloc((size_t)4 * 1024 * 128 * 2);
  unsigned short* ctxb = (unsigned short*)alloc(2048 * 1024 * 2);
  float* xres = (float*)alloc(2048 * 1024 * 4);
  float* yres = (float*)alloc(2048 * 1024 * 4);
  char*  big  = alloc((size_t)84 << 20);
  // big aliases (stream-serial lifetimes):
  float* op_s = (float*)big;                           // self out-proj partials 4x8 MB
  float* qp_c = (float*)(big + ((size_t)32 << 20));    // cross-Q partials 4x8 MB
  float* op_c = (float*)big;                           // cross out-proj partials 4x8 MB
  unsigned short* hbf = (unsigned short*)big;          // 16 MB
  float* fp   = (float*)(big + ((size_t)16 << 20));    // final partials 4x8 MB
  (void)ws_size; (void)in_sizes; (void)n_in; (void)out_size;

  // ---- prep ----
  PrepArgs pa;
  int ts = 0;
  for (int i = 0; i < 8; ++i) {
    pa.src[i] = f_W[i]; pa.dst[i] = wt + (size_t)i * 1024 * 1024;
    pa.K[i] = 1024; pa.N[i] = 1024; pa.mode[i] = 0;
    pa.tstart[i] = ts; ts += 64;                      // (1024/128)^2
  }
  pa.src[8] = f_wi0; pa.dst[8] = wc; pa.K[8] = 1024; pa.N[8] = 4096; pa.mode[8] = 1;
  pa.tstart[8] = ts; ts += 256;                       // 8 x 32
  pa.src[9] = f_wi1; pa.dst[9] = wc; pa.K[9] = 1024; pa.N[9] = 4096; pa.mode[9] = 2;
  pa.tstart[9] = ts; ts += 256;
  pa.src[10] = f_wo; pa.dst[10] = wot; pa.K[10] = 4096; pa.N[10] = 1024; pa.mode[10] = 0;
  pa.tstart[10] = ts; ts += 256;                      // 32 x 8
  pa.tstart[11] = ts;
  pa.nwt = ts;
  pa.encoded = f_encoded; pa.encbf = encbf;
  pa.table = f_table; pa.rb = rb;
  pa.nf2bf = 256;
  pa.bmdst[0] = bmext_s;  pa.bmnrg[0] = 24;
  pa.bmsrc[0][0] = f_qb; pa.bmsrc[0][1] = f_kb; pa.bmsrc[0][2] = f_vb;
  pa.bmdst[1] = bmext_c;  pa.bmnrg[1] = 16;
  pa.bmsrc[1][0] = f_kb + SEL1; pa.bmsrc[1][1] = f_vb + SEL1; pa.bmsrc[1][2] = nullptr;
  pa.bmdst[2] = bmext_q;  pa.bmnrg[2] = 8;
  pa.bmsrc[2][0] = f_qb + SEL1; pa.bmsrc[2][1] = nullptr; pa.bmsrc[2][2] = nullptr;
  pa.bmdst[3] = bmext_o;  pa.bmnrg[3] = 8;
  pa.bmsrc[3][0] = f_ob; pa.bmsrc[3][1] = nullptr; pa.bmsrc[3][2] = nullptr;
  pa.bmdst[4] = bmext_o2; pa.bmnrg[4] = 8;
  pa.bmsrc[4][0] = f_ob + SEL1; pa.bmsrc[4][1] = nullptr; pa.bmsrc[4][2] = nullptr;
  int bs = 0;
  for (int m = 0; m < 5; ++m) { pa.bmstart[m] = bs; bs += pa.bmnrg[m] * 4; }
  pa.bmstart[5] = bs;
  pa.nbm = bs;
  int totblk = pa.nwt + pa.nf2bf + 32 + pa.nbm;
  k_prep<<<dim3(totblk), dim3(256), 0, stream>>>(pa);
  k_lowc<<<dim3(256), dim3(256), 0, stream>>>(f_encoded, f_ka + SEL1, f_va + SEL1, lowext_c);

  // ---- self rms + lows ----
  k_start<<<dim3(256), dim3(256), 0, stream>>>(f_inputs, f_ln1, f_qa, f_ka, f_va, xn, lowext_s);

  // ---- big QKV fused: self (N=3072) + crossKV (N=2048), bf16 out + Vt ----
  {
    QKV2 g;
    g.s[0] = { xn, lowext_s, wt, bmext_s,
               qbf, kbf, vtb, (size_t)3072 * 128, 2, 24 };
    g.s[1] = { encbf, lowext_c, wt + (size_t)5120 * 1024, bmext_c,
               kbf2, vtb2, nullptr, (size_t)2048 * 128, 1, 16 };
    k_gemmqkv<<<dim3(24, 16, 2), dim3(256), 0, stream>>>(g);
  }

  k_flash<true, false><<<dim3(8, 64), dim3(256), 0, stream>>>(qbf, nullptr, kbf, vtb, rb, ctxb);

  // ---- self out-proj (K-ext lora_o, S4) ----
  k_lowbf<<<dim3(256), dim3(256), 0, stream>>>(ctxb, f_oa, lowext_o);
  {
    GX g;
    for (int s = 0; s < 4; ++s)
      g.s[s] = { ctxb, lowext_o, wt + (size_t)3072 * 1024, bmext_o, op_s + (size_t)s * PART,
                 (size_t)1024 * 128, 1024, 8, s * 18 / 4, (s + 1) * 18 / 4 };
    k_gemmx<<<dim3(8, 16, 4), dim3(256), 0, stream>>>(g);
  }
  k_addbrms<true><<<dim3(256), dim3(256), 0, stream>>>(op_s, f_inputs, f_ln2, xres, xn,
                                                       f_qa + SEL1, lowext_q);

  // ---- cross-Q (K-ext, S4) ----
  {
    GX g;
    for (int s = 0; s < 4; ++s)
      g.s[s] = { xn, lowext_q, wt + (size_t)4096 * 1024, bmext_q, qp_c + (size_t)s * PART,
                 (size_t)1024 * 128, 1024, 8, s * 18 / 4, (s + 1) * 18 / 4 };
    k_gemmx<<<dim3(8, 16, 4), dim3(256), 0, stream>>>(g);
  }
  k_flash<false, true><<<dim3(8, 64), dim3(256), 0, stream>>>(nullptr, qp_c, kbf2, vtb2, rb, ctxb);

  // ---- cross out-proj (K-ext lora_o sel1, S4) ----
  k_lowbf<<<dim3(256), dim3(256), 0, stream>>>(ctxb, f_oa + SEL1, lowext_o);
  {
    GX g;
    for (int s = 0; s < 4; ++s)
      g.s[s] = { ctxb, lowext_o, wt + (size_t)7168 * 1024, bmext_o2, op_c + (size_t)s * PART,
                 (size_t)1024 * 128, 1024, 8, s * 18 / 4, (s + 1) * 18 / 4 };
    k_gemmx<<<dim3(8, 16, 4), dim3(256), 0, stream>>>(g);
  }
  k_addbrms<false><<<dim3(256), dim3(256), 0, stream>>>(op_c, xres, f_ln3, yres, xn,
                                                        nullptr, nullptr);

  // ---- MLP ----
  k_mlp<<<dim3(32, 16), dim3(512), 0, stream>>>(xn, wc, hbf);
  k_gemm1s<<<dim3(8, 16, 4), dim3(256), 0, stream>>>(hbf, wot, fp, PART, 1024, 4096, 4096, 1024);
  k_sum4<<<dim3(2048), dim3(256), 0, stream>>>(fp, PART, yres, (float*)d_out);
}

// Round 8
// 507.650 us; speedup vs baseline: 1.0922x; 1.0922x over previous
//
#include <hip/hip_runtime.h>
#include <math.h>

// ---------------------------------------------------------------------------
// LoRA T5 decoder layer on MI355X (gfx950).
// B=4, L=ENC=512, D=1024, H=16, HD=64, MLP=4096, R=32.
// R17->R18: four k_prep transpose variants all pinned at ~50us @2.0TB/s ->
// treat the prep stream as fixed cost and HIDE work under it. k_start and
// k_lowc (independent, compute-bound) are fused into k_prep as leading
// branches (they fill CU gaps behind the memory-bound transpose stream and
// remove 2 launch gaps). LDS per branch kept <= the 33.8KB transpose tile:
// k_start epilogue j-split (pacc 24->12KB), k_lowc rows staged bf16 (32->16KB)
// + j-split (pacc 16->8KB). Block order: start, lowc, bmext, relbias, encbf,
// transposes last (uniform tail). Everything else unchanged from R17.
// ---------------------------------------------------------------------------

#define DEV __device__ __forceinline__

typedef __bf16 bf16x8 __attribute__((ext_vector_type(8)));
typedef float floatx4 __attribute__((ext_vector_type(4)));

typedef __attribute__((address_space(1))) void* gas_ptr;
typedef __attribute__((address_space(3))) void* las_ptr;

DEV unsigned short f2bf(float f) {
  union { float f; unsigned int u; } v; v.f = f;
  unsigned int r = v.u + 0x7fffu + ((v.u >> 16) & 1u);
  return (unsigned short)(r >> 16);
}
DEV float bf2f(unsigned short u) {
  union { unsigned int u; float f; } v; v.u = ((unsigned int)u) << 16;
  return v.f;
}

#define GLOAD_LDS16(g, l) __builtin_amdgcn_global_load_lds((gas_ptr)(g), (las_ptr)(l), 16, 0, 0)

// Swizzled staging, 128B rows: LDS physical chunk-col p of row r holds logical
// chunk (p ^ (r&7)). Lane p=(lane&7), r&7=(lane>>3)&7 -> load logical col
// (lane&7)^((lane>>3)&7). Same 128-B segments per wave => coalescing kept.
template<int NW>
DEV void stage_tile_sw(const char* gbase, char* lds, int nrows, int ldbytes, int wave, int lane) {
  int nchunks = nrows >> 3;
  int colb = (((lane & 7) ^ ((lane >> 3) & 7)) << 4);
  for (int c = wave; c < nchunks; c += NW) {
    int row = (c << 3) + (lane >> 3);
    GLOAD_LDS16(gbase + (size_t)row * ldbytes + colb, lds + (c << 10));
  }
}

// Swizzled staging, 256B rows (16 chunks/row): phys chunk p of row r holds
// logical (p ^ (r&7)). Here r&7 depends on c parity: r = (c<<2)+(lane>>4).
template<int NW>
DEV void stage_tile256_sw(const char* gbase, char* lds, int nrows, int ldbytes, int wave, int lane) {
  int nchunks = nrows >> 2;
  for (int c = wave; c < nchunks; c += NW) {
    int row = (c << 2) + (lane >> 4);
    int key = row & 7;
    int colb = ((lane & 15) ^ key) << 4;
    GLOAD_LDS16(gbase + (size_t)row * ldbytes + colb, lds + (c << 10));
  }
}

// ---------------- generic bf16 GEMM core (fp32 out), 128x128 tile ----------
// Swizzled LDS: fragment read col16 = ((kk>>3)+quad) ^ (l15&7).
template<int WM, int WN>
DEV void gemm_core(const unsigned short* A, const unsigned short* Bt, float* C,
                   int K, int lda, int ldb, int ldc, int m0, int n0,
                   char* ldsA, char* ldsB) {
  constexpr int NW = WM * WN;
  const int tid  = threadIdx.x;
  const int lane = tid & 63;
  const int wave = tid >> 6;
  const int wm   = wave % WM;
  const int wn   = wave / WM;
  const int quad = lane >> 4;
  const int l15  = lane & 15;
  const int key  = l15 & 7;

  floatx4 acc[4][4];
#pragma unroll
  for (int i = 0; i < 4; ++i)
#pragma unroll
    for (int j = 0; j < 4; ++j) acc[i][j] = (floatx4){0.f, 0.f, 0.f, 0.f};

  const char* gA = (const char*)(A + (size_t)m0 * lda);
  const char* gB = (const char*)(Bt + (size_t)n0 * ldb);

  for (int k0 = 0; k0 < K; k0 += 64) {
    stage_tile_sw<NW>(gA + (size_t)k0 * 2, ldsA, WM * 64, lda * 2, wave, lane);
    stage_tile_sw<NW>(gB + (size_t)k0 * 2, ldsB, WN * 64, ldb * 2, wave, lane);
    __syncthreads();
#pragma unroll
    for (int kk = 0; kk < 64; kk += 32) {
      bf16x8 af[4], bv[4];
      int off = (((kk >> 3) + quad) ^ key) << 4;
      const char* baseA = ldsA + (size_t)(wm * 64 + l15) * 128 + off;
      const char* baseB = ldsB + (size_t)(wn * 64 + l15) * 128 + off;
#pragma unroll
      for (int mi = 0; mi < 4; ++mi) af[mi] = *(const bf16x8*)(baseA + mi * 2048);
#pragma unroll
      for (int ni = 0; ni < 4; ++ni) bv[ni] = *(const bf16x8*)(baseB + ni * 2048);
#pragma unroll
      for (int mi = 0; mi < 4; ++mi)
#pragma unroll
        for (int ni = 0; ni < 4; ++ni)
          acc[mi][ni] = __builtin_amdgcn_mfma_f32_16x16x32_bf16(af[mi], bv[ni], acc[mi][ni], 0, 0, 0);
    }
    __syncthreads();
  }

#pragma unroll
  for (int mi = 0; mi < 4; ++mi) {
#pragma unroll
    for (int r = 0; r < 4; ++r) {
      int row = m0 + wm * 64 + mi * 16 + quad * 4 + r;
#pragma unroll
      for (int ni = 0; ni < 4; ++ni) {
        int col = n0 + wn * 64 + ni * 16 + l15;
        C[(size_t)row * ldc + col] = acc[mi][ni][r];
      }
    }
  }
}

__global__ __launch_bounds__(256) void k_gemm1s(const unsigned short* A, const unsigned short* Bt,
                                                float* Cpart, size_t pstride,
                                                int Kchunk, int lda, int ldb, int ldc) {
  __shared__ char lds[32768];
  int s = blockIdx.z;
  size_t koff = (size_t)s * Kchunk;
  gemm_core<2, 2>(A + koff, Bt + koff, Cpart + (size_t)s * pstride,
                  Kchunk, lda, ldb, ldc,
                  blockIdx.y * 128, blockIdx.x * 128, lds, lds + 16384);
}

// ---------------- K-extended GEMM: C = [A0|Aext] @ [B0|Bext(b)]^T ----------
struct GXSlice {
  const unsigned short* A0;
  const unsigned short* Aext;
  const unsigned short* B0;
  const unsigned short* Bext;
  float* C;
  size_t bextb;            // per-b element stride of Bext (= N*128)
  int ldc, nxa, it0, it1;
};
struct GX { GXSlice s[4]; };

__global__ __launch_bounds__(256) void k_gemmx(GX g) {
  __shared__ char lds[32768];
  char* ldsA = lds;
  char* ldsB = lds + 16384;
  GXSlice sl = g.s[blockIdx.z];
  if ((int)blockIdx.x >= sl.nxa) return;
  const int m0 = blockIdx.y * 128, n0 = blockIdx.x * 128;
  const int b = m0 >> 9;
  const int tid = threadIdx.x, lane = tid & 63, wave = tid >> 6;
  const int wm = wave & 1, wn = wave >> 1;
  const int quad = lane >> 4, l15 = lane & 15;
  const int key = l15 & 7;

  floatx4 acc[4][4];
#pragma unroll
  for (int i = 0; i < 4; ++i)
#pragma unroll
    for (int j = 0; j < 4; ++j) acc[i][j] = (floatx4){0.f, 0.f, 0.f, 0.f};

  for (int it = sl.it0; it < sl.it1; ++it) {
    if (it < 16) {
      stage_tile_sw<4>((const char*)sl.A0 + (size_t)m0 * 2048 + it * 128, ldsA, 128, 2048, wave, lane);
      stage_tile_sw<4>((const char*)sl.B0 + (size_t)n0 * 2048 + it * 128, ldsB, 128, 2048, wave, lane);
    } else {
      int eb = (it - 16) * 128;
      stage_tile_sw<4>((const char*)sl.Aext + (size_t)m0 * 256 + eb, ldsA, 128, 256, wave, lane);
      stage_tile_sw<4>((const char*)(sl.Bext + (size_t)b * sl.bextb) + (size_t)n0 * 256 + eb,
                       ldsB, 128, 256, wave, lane);
    }
    __syncthreads();
#pragma unroll
    for (int kk = 0; kk < 64; kk += 32) {
      bf16x8 af[4], bv[4];
      int off = (((kk >> 3) + quad) ^ key) << 4;
      const char* baseA = ldsA + (size_t)(wm * 64 + l15) * 128 + off;
      const char* baseB = ldsB + (size_t)(wn * 64 + l15) * 128 + off;
#pragma unroll
      for (int mi = 0; mi < 4; ++mi) af[mi] = *(const bf16x8*)(baseA + mi * 2048);
#pragma unroll
      for (int ni = 0; ni < 4; ++ni) bv[ni] = *(const bf16x8*)(baseB + ni * 2048);
#pragma unroll
      for (int mi = 0; mi < 4; ++mi)
#pragma unroll
        for (int ni = 0; ni < 4; ++ni)
          acc[mi][ni] = __builtin_amdgcn_mfma_f32_16x16x32_bf16(af[mi], bv[ni], acc[mi][ni], 0, 0, 0);
    }
    __syncthreads();
  }

#pragma unroll
  for (int mi = 0; mi < 4; ++mi) {
#pragma unroll
    for (int r = 0; r < 4; ++r) {
      int row = m0 + wm * 64 + mi * 16 + quad * 4 + r;
#pragma unroll
      for (int ni = 0; ni < 4; ++ni) {
        int col = n0 + wn * 64 + ni * 16 + l15;
        sl.C[(size_t)row * sl.ldc + col] = acc[mi][ni][r];
      }
    }
  }
}

// ---------------- fused QKV GEMM: bf16 epilogue + in-LDS V transpose ------
struct QKVSlice {
  const unsigned short* A0;
  const unsigned short* Aext;
  const unsigned short* B0;
  const unsigned short* Bext;
  unsigned short* sec0;
  unsigned short* sec1;
  unsigned short* sec2;
  size_t bextb;
  int vsec, nxa;
};
struct QKV2 { QKVSlice s[2]; };

__global__ __launch_bounds__(256) void k_gemmqkv(QKV2 g) {
  __shared__ char lds[34816];          // 32KB staging; reused: 4 x 8704B vbuf
  char* ldsA = lds;
  char* ldsB = lds + 16384;
  QKVSlice sl = g.s[blockIdx.z];
  if ((int)blockIdx.x >= sl.nxa) return;
  const int m0 = blockIdx.y * 128, n0 = blockIdx.x * 128;
  const int b = m0 >> 9;
  const int tid = threadIdx.x, lane = tid & 63, wave = tid >> 6;
  const int wm = wave & 1, wn = wave >> 1;
  const int quad = lane >> 4, l15 = lane & 15;
  const int key = l15 & 7;

  floatx4 acc[4][4];
#pragma unroll
  for (int i = 0; i < 4; ++i)
#pragma unroll
    for (int j = 0; j < 4; ++j) acc[i][j] = (floatx4){0.f, 0.f, 0.f, 0.f};

  for (int it = 0; it < 18; ++it) {
    if (it < 16) {
      stage_tile_sw<4>((const char*)sl.A0 + (size_t)m0 * 2048 + it * 128, ldsA, 128, 2048, wave, lane);
      stage_tile_sw<4>((const char*)sl.B0 + (size_t)n0 * 2048 + it * 128, ldsB, 128, 2048, wave, lane);
    } else {
      int eb = (it - 16) * 128;
      stage_tile_sw<4>((const char*)sl.Aext + (size_t)m0 * 256 + eb, ldsA, 128, 256, wave, lane);
      stage_tile_sw<4>((const char*)(sl.Bext + (size_t)b * sl.bextb) + (size_t)n0 * 256 + eb,
                       ldsB, 128, 256, wave, lane);
    }
    __syncthreads();
#pragma unroll
    for (int kk = 0; kk < 64; kk += 32) {
      bf16x8 af[4], bv[4];
      int off = (((kk >> 3) + quad) ^ key) << 4;
      const char* baseA = ldsA + (size_t)(wm * 64 + l15) * 128 + off;
      const char* baseB = ldsB + (size_t)(wn * 64 + l15) * 128 + off;
#pragma unroll
      for (int mi = 0; mi < 4; ++mi) af[mi] = *(const bf16x8*)(baseA + mi * 2048);
#pragma unroll
      for (int ni = 0; ni < 4; ++ni) bv[ni] = *(const bf16x8*)(baseB + ni * 2048);
#pragma unroll
      for (int mi = 0; mi < 4; ++mi)
#pragma unroll
        for (int ni = 0; ni < 4; ++ni)
          acc[mi][ni] = __builtin_amdgcn_mfma_f32_16x16x32_bf16(af[mi], bv[ni], acc[mi][ni], 0, 0, 0);
    }
    __syncthreads();
  }

  const int sec = n0 >> 10;
  const int nloc = n0 & 1023;
  if (sec != sl.vsec) {
    // row-major bf16 store (q or k section)
    unsigned short* dst = (sec == 0) ? sl.sec0 : sl.sec1;
#pragma unroll
    for (int mi = 0; mi < 4; ++mi)
#pragma unroll
      for (int r = 0; r < 4; ++r) {
        int row = m0 + wm * 64 + mi * 16 + quad * 4 + r;
        unsigned short* drow = dst + (size_t)row * 1024 + nloc + wn * 64;
#pragma unroll
        for (int ni = 0; ni < 4; ++ni)
          drow[ni * 16 + l15] = f2bf(acc[mi][ni][r]);
      }
  } else {
    // V section: per-wave 64x64 transpose via LDS (staging LDS is free here).
    unsigned short* vdstb = (sl.vsec == 1) ? sl.sec1 : sl.sec2;
    char* vbuf = lds + (size_t)(wm * 2 + wn) * 8704;   // [64 d][136B] (68 elem rows)
#pragma unroll
    for (int ni = 0; ni < 4; ++ni)
#pragma unroll
      for (int mi = 0; mi < 4; ++mi) {
        unsigned long long pk =
            (unsigned long long)f2bf(acc[mi][ni][0])
          | ((unsigned long long)f2bf(acc[mi][ni][1]) << 16)
          | ((unsigned long long)f2bf(acc[mi][ni][2]) << 32)
          | ((unsigned long long)f2bf(acc[mi][ni][3]) << 48);
        *(unsigned long long*)(vbuf + (size_t)(ni * 16 + l15) * 136 + (mi * 16 + quad * 4) * 2) = pk;
      }
    __syncthreads();
    int dbase = nloc + wn * 64;        // multiple of 64 -> one head per wave
    int h = dbase >> 6;
    int kb = (m0 & 511) + wm * 64;
    unsigned short* vdst = vdstb + (size_t)(b * 16 + h) * 64 * 512;
    int lh = lane >> 3, ll = lane & 7;
#pragma unroll
    for (int i = 0; i < 8; ++i) {
      int d = i * 8 + lh;
      const char* p = vbuf + (size_t)d * 136 + ll * 16;
      unsigned long long lo = *(const unsigned long long*)p;
      unsigned long long hi = *(const unsigned long long*)(p + 8);
      uint4 v;
      v.x = (unsigned)lo; v.y = (unsigned)(lo >> 32);
      v.z = (unsigned)hi; v.w = (unsigned)(hi >> 32);
      *(uint4*)(vdst + (size_t)d * 512 + kb + ll * 8) = v;
    }
  }
}

// ---------------- flash attention (XOR-swizzled LDS) ----------------------
template<bool CAUSAL, bool QSUM>
__global__ __launch_bounds__(256) void k_flash(const unsigned short* qmat, const float* qparts,
                                               const unsigned short* kmat, const unsigned short* vt,
                                               const float* rb, unsigned short* ctxb) {
  __shared__ char ldsQ[8192];    // [64 q][64 d]
  __shared__ char ldsK[16384];   // [128 k][64 d]
  __shared__ char ldsV[16384];   // [64 d][128 k]
  __shared__ char ldsP[16384];   // [64 q][128 k]
  __shared__ float lrb[512];

  const size_t PART = (size_t)2048 * 1024;
  const int z = blockIdx.y, b = z >> 4, h = z & 15;
  const int q0 = blockIdx.x * 64;
  const int tid = threadIdx.x, lane = tid & 63, wave = tid >> 6;
  const int quad = lane >> 4, l15 = lane & 15;
  const int key = l15 & 7;

  const unsigned short* K = kmat + (size_t)b * 512 * 1024 + h * 64;
  const unsigned short* V = vt + (size_t)z * 64 * 512;

  if (QSUM) {
#pragma unroll
    for (int rr = 0; rr < 4; ++rr) {
      int row = rr * 16 + (tid >> 4);
      int c4 = tid & 15;
      const float* src = qparts + (size_t)(q0 + row) * 1024 + h * 64 + c4 * 4;
      float4 s0 = *(const float4*)src;
      float4 s1 = *(const float4*)(src + PART);
      float4 s2 = *(const float4*)(src + 2 * PART);
      float4 s3 = *(const float4*)(src + 3 * PART);
      ushort4 o;
      o.x = f2bf(s0.x + s1.x + s2.x + s3.x);
      o.y = f2bf(s0.y + s1.y + s2.y + s3.y);
      o.z = f2bf(s0.z + s1.z + s2.z + s3.z);
      o.w = f2bf(s0.w + s1.w + s2.w + s3.w);
      // 8B granule: logical chunk = c4>>1, half = c4&1; swizzle the chunk.
      int qoff = (((c4 >> 1) ^ (row & 7)) << 4) | ((c4 & 1) << 3);
      *(ushort4*)(ldsQ + (size_t)row * 128 + qoff) = o;
    }
  } else {
    const unsigned short* Q = qmat + (size_t)b * 512 * 1024 + h * 64;
    stage_tile_sw<4>((const char*)(Q + (size_t)q0 * 1024), ldsQ, 64, 2048, wave, lane);
  }
  if (CAUSAL)
    for (int i = tid; i < 512; i += 256) lrb[i] = rb[h * 512 + i];

  float m_run[4], l_run[4];
  floatx4 oacc[4];
#pragma unroll
  for (int r = 0; r < 4; ++r) { m_run[r] = -1e30f; l_run[r] = 0.f; }
#pragma unroll
  for (int ni = 0; ni < 4; ++ni) oacc[ni] = (floatx4){0.f, 0.f, 0.f, 0.f};

  const int ktend = CAUSAL ? (blockIdx.x / 2 + 1) : 4;
  for (int kt = 0; kt < ktend; ++kt) {
    __syncthreads();
    stage_tile_sw<4>((const char*)(K + (size_t)kt * 128 * 1024), ldsK, 128, 2048, wave, lane);
    stage_tile256_sw<4>((const char*)(V + kt * 128), ldsV, 64, 1024, wave, lane);
    __syncthreads();

    floatx4 sacc[8];
#pragma unroll
    for (int ct = 0; ct < 8; ++ct) sacc[ct] = (floatx4){0.f, 0.f, 0.f, 0.f};
    const size_t qrow = (size_t)(wave * 16 + l15) * 128;
#pragma unroll
    for (int kd = 0; kd < 2; ++kd) {
      int offq = ((quad + kd * 4) ^ key) << 4;
      bf16x8 af = *(const bf16x8*)(ldsQ + qrow + offq);
#pragma unroll
      for (int ct = 0; ct < 8; ++ct) {
        bf16x8 bfv = *(const bf16x8*)(ldsK + (size_t)(ct * 16 + l15) * 128 + offq);
        sacc[ct] = __builtin_amdgcn_mfma_f32_16x16x32_bf16(af, bfv, sacc[ct], 0, 0, 0);
      }
    }

    float sv[8][4];
#pragma unroll
    for (int ct = 0; ct < 8; ++ct)
#pragma unroll
      for (int r = 0; r < 4; ++r) {
        float v = sacc[ct][r] * 0.125f;
        if (CAUSAL) {
          int qq = q0 + wave * 16 + quad * 4 + r;
          int kk = kt * 128 + ct * 16 + l15;
          v = (kk <= qq) ? v + lrb[qq - kk] : -1e30f;
        }
        sv[ct][r] = v;
      }

    float mx[4];
#pragma unroll
    for (int r = 0; r < 4; ++r) {
      mx[r] = sv[0][r];
#pragma unroll
      for (int ct = 1; ct < 8; ++ct) mx[r] = fmaxf(mx[r], sv[ct][r]);
    }
#pragma unroll
    for (int o = 1; o < 16; o <<= 1)
#pragma unroll
      for (int r = 0; r < 4; ++r) mx[r] = fmaxf(mx[r], __shfl_xor(mx[r], o));

    float alpha[4], rs[4];
#pragma unroll
    for (int r = 0; r < 4; ++r) {
      float mn = fmaxf(m_run[r], mx[r]);
      alpha[r] = __expf(m_run[r] - mn);
      m_run[r] = mn;
      rs[r] = 0.f;
    }
#pragma unroll
    for (int ct = 0; ct < 8; ++ct)
#pragma unroll
      for (int r = 0; r < 4; ++r) {
        float p = __expf(sv[ct][r] - m_run[r]);
        sv[ct][r] = p;
        rs[r] += p;
      }
#pragma unroll
    for (int o = 1; o < 16; o <<= 1)
#pragma unroll
      for (int r = 0; r < 4; ++r) rs[r] += __shfl_xor(rs[r], o);
#pragma unroll
    for (int r = 0; r < 4; ++r) l_run[r] = l_run[r] * alpha[r] + rs[r];
#pragma unroll
    for (int ni = 0; ni < 4; ++ni)
#pragma unroll
      for (int r = 0; r < 4; ++r) oacc[ni][r] *= alpha[r];

#pragma unroll
    for (int ct = 0; ct < 8; ++ct)
#pragma unroll
      for (int r = 0; r < 4; ++r) {
        int prow_w = wave * 16 + quad * 4 + r;
        int kidx = ct * 16 + l15;
        int pb = (((kidx >> 3) ^ (prow_w & 7)) << 4) | ((kidx & 7) << 1);
        *(unsigned short*)(ldsP + (size_t)prow_w * 256 + pb) = f2bf(sv[ct][r]);
      }
    __syncthreads();

    const size_t prow = (size_t)(wave * 16 + l15) * 256;
#pragma unroll
    for (int kk = 0; kk < 4; ++kk) {
      int offp = ((quad + kk * 4) ^ key) << 4;
      bf16x8 pf = *(const bf16x8*)(ldsP + prow + offp);
#pragma unroll
      for (int ni = 0; ni < 4; ++ni) {
        bf16x8 vf8 = *(const bf16x8*)(ldsV + (size_t)(ni * 16 + l15) * 256 + offp);
        oacc[ni] = __builtin_amdgcn_mfma_f32_16x16x32_bf16(pf, vf8, oacc[ni], 0, 0, 0);
      }
    }
  }

#pragma unroll
  for (int r = 0; r < 4; ++r) {
    int q = q0 + wave * 16 + quad * 4 + r;
    float inv = 1.0f / l_run[r];
    unsigned short* dst = ctxb + ((size_t)b * 512 + q) * 1024 + h * 64;
#pragma unroll
    for (int ni = 0; ni < 4; ++ni)
      dst[ni * 16 + l15] = f2bf(oacc[ni][r] * inv);
  }
}

// ---------------- fused MLP (swizzled LDS) ----------------
__global__ __launch_bounds__(512) void k_mlp(const unsigned short* A, const unsigned short* Wc,
                                             unsigned short* hbf) {
  __shared__ char lds[49152];
  char* ldsA = lds;
  char* ldsB = lds + 16384;
  const int m0 = blockIdx.y * 128;
  const int n0 = blockIdx.x * 128;
  const int tid = threadIdx.x, lane = tid & 63, wave = tid >> 6;
  const int half = wave >> 2, wl = wave & 3;
  const int wm = wl & 1, wn = wl >> 1;
  const int quad = lane >> 4, l15 = lane & 15;
  const int key = l15 & 7;

  floatx4 acc[4][4];
#pragma unroll
  for (int i = 0; i < 4; ++i)
#pragma unroll
    for (int j = 0; j < 4; ++j) acc[i][j] = (floatx4){0.f, 0.f, 0.f, 0.f};

  const char* gA = (const char*)(A + (size_t)m0 * 1024);
  const char* gB = (const char*)(Wc + (size_t)blockIdx.x * 256 * 1024);

  for (int k0 = 0; k0 < 1024; k0 += 64) {
    stage_tile_sw<8>(gA + (size_t)k0 * 2, ldsA, 128, 2048, wave, lane);
    stage_tile_sw<8>(gB + (size_t)k0 * 2, ldsB, 256, 2048, wave, lane);
    __syncthreads();
#pragma unroll
    for (int kk = 0; kk < 64; kk += 32) {
      bf16x8 af[4], bv[4];
      int off = (((kk >> 3) + quad) ^ key) << 4;
      const char* baseA = ldsA + (size_t)(wm * 64 + l15) * 128 + off;
      const char* baseB = ldsB + (size_t)(half * 128 + wn * 64 + l15) * 128 + off;
#pragma unroll
      for (int mi = 0; mi < 4; ++mi) af[mi] = *(const bf16x8*)(baseA + mi * 2048);
#pragma unroll
      for (int ni = 0; ni < 4; ++ni) bv[ni] = *(const bf16x8*)(baseB + ni * 2048);
#pragma unroll
      for (int mi = 0; mi < 4; ++mi)
#pragma unroll
        for (int ni = 0; ni < 4; ++ni)
          acc[mi][ni] = __builtin_amdgcn_mfma_f32_16x16x32_bf16(af[mi], bv[ni], acc[mi][ni], 0, 0, 0);
    }
    __syncthreads();
  }

  if (half == 1) {
#pragma unroll
    for (int mi = 0; mi < 4; ++mi)
#pragma unroll
      for (int r = 0; r < 4; ++r) {
        int row = wm * 64 + mi * 16 + quad * 4 + r;
#pragma unroll
        for (int ni = 0; ni < 4; ++ni) {
          int col = wn * 64 + ni * 16 + l15;
          *(unsigned short*)(ldsB + (size_t)row * 256 + col * 2) = f2bf(acc[mi][ni][r]);
        }
      }
  }
  __syncthreads();
  if (half == 0) {
#pragma unroll
    for (int mi = 0; mi < 4; ++mi)
#pragma unroll
      for (int r = 0; r < 4; ++r) {
        int row = wm * 64 + mi * 16 + quad * 4 + r;
#pragma unroll
        for (int ni = 0; ni < 4; ++ni) {
          int col = wn * 64 + ni * 16 + l15;
          float h1 = bf2f(*(const unsigned short*)(ldsB + (size_t)row * 256 + col * 2));
          float g = acc[mi][ni][r];
          float v = 0.5f * g * (1.0f + erff(g * 0.70710678f)) * h1;
          hbf[(size_t)(m0 + row) * 4096 + n0 + col] = f2bf(v);
        }
      }
  }
}

// ---------------- mega-prep: start + lowc + bmext + relbias + encbf + T ---
struct PrepArgs {
  const float* src[11];
  unsigned short* dst[11];
  int K[11], N[11], mode[11];
  int tstart[12];
  const float* encoded;
  unsigned short* encbf;
  const float* table;
  float* rb;
  unsigned short* bmdst[5];
  const float* bmsrc[5][3];
  int bmnrg[5];
  int bmstart[6];
  int nwt, nf2bf, nbm;
  // fused k_start:
  const float* xin; const float* ln1;
  const float* qa; const float* ka; const float* va;
  unsigned short* xnp; unsigned short* lows;
  // fused k_lowc:
  const float* lca0; const float* lca1;
  unsigned short* lowc;
};
__global__ __launch_bounds__(256, 2) void k_prep(PrepArgs a) {
  __shared__ char shm[33792];
  int bid = blockIdx.x;
  int t = threadIdx.x;
  if (bid < 256) {
    // ---- k_start: rmsnorm + self q/k/v lows (j-split epilogue, 28.2KB) ----
    unsigned short (*lrows)[1024] = (unsigned short(*)[1024])shm;   // 16KB
    float* pacc = (float*)(shm + 16384);                            // 12KB [3][4][8][32]
    float* red  = (float*)(shm + 28672);
    int row0 = bid * 8;
    int b = row0 >> 9;
    float4 s4 = ((const float4*)a.ln1)[t];
    for (int j = 0; j < 8; ++j) {
      int row = row0 + j;
      float4 v = ((const float4*)(a.xin + (size_t)row * 1024))[t];
      float ss = v.x * v.x + v.y * v.y + v.z * v.z + v.w * v.w;
      for (int o = 32; o; o >>= 1) ss += __shfl_down(ss, o);
      if ((t & 63) == 0) red[t >> 6] = ss;
      __syncthreads();
      float tot = red[0] + red[1] + red[2] + red[3];
      float rs = rsqrtf(tot * (1.0f / 1024.0f) + 1e-6f);
      ushort4 o;
      o.x = f2bf(v.x * rs * s4.x); o.y = f2bf(v.y * rs * s4.y);
      o.z = f2bf(v.z * rs * s4.z); o.w = f2bf(v.w * rs * s4.w);
      ((ushort4*)(a.xnp + (size_t)row * 1024))[t] = o;
      *(ushort4*)(&lrows[j][t * 4]) = o;
      __syncthreads();
    }
    int r = t & 31, g = t >> 5;
    float acc[3][8];
#pragma unroll
    for (int p = 0; p < 3; ++p)
#pragma unroll
      for (int j = 0; j < 8; ++j) acc[p][j] = 0.f;
    const float* aq = a.qa + (size_t)b * 65536;
    const float* ak = a.ka + (size_t)b * 65536;
    const float* av = a.va + (size_t)b * 65536;
    for (int i = 0; i < 128; ++i) {
      int k = g * 128 + i;
      float a0 = aq[(size_t)k * 32 + r];
      float a1 = ak[(size_t)k * 32 + r];
      float a2 = av[(size_t)k * 32 + r];
#pragma unroll
      for (int j = 0; j < 8; ++j) {
        float xv = bf2f(lrows[j][k]);
        acc[0][j] += xv * a0;
        acc[1][j] += xv * a1;
        acc[2][j] += xv * a2;
      }
    }
    for (int jh = 0; jh < 2; ++jh) {
      __syncthreads();
#pragma unroll
      for (int p = 0; p < 3; ++p)
#pragma unroll
        for (int jj = 0; jj < 4; ++jj)
          pacc[((p * 4 + jj) * 8 + g) * 32 + r] = acc[p][jh * 4 + jj];
      __syncthreads();
      for (int jj = 0; jj < 4; ++jj) {
        int row = row0 + jh * 4 + jj;
        if (t < 96) {
          int p = t >> 5, r2 = t & 31;
          float s = 0.f;
          for (int gg = 0; gg < 8; ++gg) s += pacc[((p * 4 + jj) * 8 + gg) * 32 + r2];
          a.lows[(size_t)row * 128 + p * 32 + r2] = f2bf(s);
        } else if (t < 128) {
          a.lows[(size_t)row * 128 + t] = 0;
        }
      }
    }
    return;
  }
  bid -= 256;
  if (bid < 256) {
    // ---- k_lowc: cross-KV lows (bf16 rows + j-split, 24KB) ----
    unsigned short* rowsB = (unsigned short*)shm;    // [8][1024] bf16 16KB
    float* pacc = (float*)(shm + 16384);             // 8KB [2][4][8][32]
    int row0 = bid * 8;
    int b = row0 >> 9;
    for (int j = 0; j < 8; ++j) {
      float4 v = ((const float4*)(a.encoded + (size_t)(row0 + j) * 1024))[t];
      ushort4 o;
      o.x = f2bf(v.x); o.y = f2bf(v.y); o.z = f2bf(v.z); o.w = f2bf(v.w);
      *(ushort4*)(rowsB + j * 1024 + t * 4) = o;
    }
    __syncthreads();
    int r = t & 31, g = t >> 5;
    float acc[2][8];
#pragma unroll
    for (int p = 0; p < 2; ++p)
#pragma unroll
      for (int j = 0; j < 8; ++j) acc[p][j] = 0.f;
    const float* a0 = a.lca0 + (size_t)b * 65536;
    const float* a1 = a.lca1 + (size_t)b * 65536;
    for (int i = 0; i < 128; ++i) {
      int k = g * 128 + i;
      float ak = a0[(size_t)k * 32 + r];
      float av = a1[(size_t)k * 32 + r];
#pragma unroll
      for (int j = 0; j < 8; ++j) {
        float x = bf2f(rowsB[j * 1024 + k]);
        acc[0][j] += x * ak;
        acc[1][j] += x * av;
      }
    }
    for (int jh = 0; jh < 2; ++jh) {
      __syncthreads();
#pragma unroll
      for (int p = 0; p < 2; ++p)
#pragma unroll
        for (int jj = 0; jj < 4; ++jj)
          pacc[((p * 4 + jj) * 8 + g) * 32 + r] = acc[p][jh * 4 + jj];
      __syncthreads();
      for (int jj = 0; jj < 4; ++jj) {
        int row = row0 + jh * 4 + jj;
        if (t < 64) {
          int p = t >> 5, r2 = t & 31;
          float s = 0.f;
          for (int gg = 0; gg < 8; ++gg) s += pacc[((p * 4 + jj) * 8 + gg) * 32 + r2];
          a.lowc[(size_t)row * 128 + p * 32 + r2] = f2bf(s);
        } else if (t < 128) {
          a.lowc[(size_t)row * 128 + t] = 0;
        }
      }
    }
    return;
  }
  bid -= 256;
  if (bid < a.nbm) {
    // bmext fill: Bext[b][row=n0+n][c] = (c>>5==sec) ? b_sec[b][c&31][(n0&1023)+n] : 0
    int m = 0;
    while (m < 4 && bid >= a.bmstart[m + 1]) ++m;
    int idx = bid - a.bmstart[m];
    int nrg = a.bmnrg[m];
    int b = idx / nrg, rg = idx % nrg;
    int n0 = rg * 128;
    int sec = n0 >> 10;
    const float* src = a.bmsrc[m][sec] + (size_t)b * 65536;
    unsigned short* dst = a.bmdst[m] + ((size_t)b * nrg * 128 + n0) * 128;
    int n = t & 127, coff = (t >> 7) * 64;
    int ncol = (n0 & 1023) + n;
    unsigned short* drow = dst + (size_t)n * 128 + coff;
    for (int cg = 0; cg < 16; cg += 8) {
      float vv[8][4];
#pragma unroll
      for (int cc = 0; cc < 8; ++cc)
#pragma unroll
        for (int e = 0; e < 4; ++e) {
          int c = coff + (cg + cc) * 4 + e;
          vv[cc][e] = ((c >> 5) == sec) ? src[(size_t)(c & 31) * 1024 + ncol] : 0.f;
        }
#pragma unroll
      for (int cc = 0; cc < 8; ++cc) {
        ushort4 o;
        o.x = f2bf(vv[cc][0]); o.y = f2bf(vv[cc][1]);
        o.z = f2bf(vv[cc][2]); o.w = f2bf(vv[cc][3]);
        *(ushort4*)(drow + (cg + cc) * 4) = o;
      }
    }
    return;
  }
  bid -= a.nbm;
  if (bid < 32) {
    int i = bid * 256 + t;
    if (i < 16 * 512) {
      int h = i >> 9, d = i & 511;
      int bucket;
      if (d < 16) bucket = d;
      else {
        int lb = 16 + (int)(logf((float)d / 16.0f) / logf(8.0f) * 16.0f);
        bucket = lb < 31 ? lb : 31;
      }
      a.rb[i] = a.table[bucket * 16 + h];
    }
    return;
  }
  bid -= 32;
  if (bid < a.nf2bf) {
    // 256 blocks x 8 batched float4 per thread (2M floats total).
    const float4* src = (const float4*)a.encoded;
    ushort4* dst = (ushort4*)a.encbf;
    int base = bid * 2048 + t;
    float4 v[8];
#pragma unroll
    for (int i = 0; i < 8; ++i) v[i] = src[base + i * 256];
#pragma unroll
    for (int i = 0; i < 8; ++i) {
      ushort4 o;
      o.x = f2bf(v[i].x); o.y = f2bf(v[i].y); o.z = f2bf(v[i].z); o.w = f2bf(v[i].w);
      dst[base + i * 256] = o;
    }
    return;
  }
  bid -= a.nf2bf;
  {
    // weight transpose: 128x128 tiles, in-register 4x4 transpose, LDS [n][k]
    int z = 0;
    while (z < 10 && bid >= a.tstart[z + 1]) ++z;
    int tile = bid - a.tstart[z];
    int N = a.N[z], K = a.K[z], mode = a.mode[z];
    int ntn = N >> 7;
    int tn = tile % ntn, tk = tile / ntn;
    const float* src = a.src[z] + (size_t)(tk * 128) * N + tn * 128;
#pragma unroll
    for (int i = 0; i < 4; ++i) {
      int c = i * 256 + t;                // 0..1023
      int k4 = c >> 5;                    // 0..31 (k0 = k4*4)
      int c4 = c & 31;                    // col4 (n0 = c4*4)
      const float* p = src + (size_t)(k4 * 4) * N + c4 * 4;
      float4 v0 = *(const float4*)(p);
      float4 v1 = *(const float4*)(p + N);
      float4 v2 = *(const float4*)(p + 2 * (size_t)N);
      float4 v3 = *(const float4*)(p + 3 * (size_t)N);
      char* base = shm + (size_t)(c4 * 4) * 264 + k4 * 8;
      ushort4 o;
      o.x = f2bf(v0.x); o.y = f2bf(v1.x); o.z = f2bf(v2.x); o.w = f2bf(v3.x);
      *(ushort4*)(base) = o;
      o.x = f2bf(v0.y); o.y = f2bf(v1.y); o.z = f2bf(v2.y); o.w = f2bf(v3.y);
      *(ushort4*)(base + 264) = o;
      o.x = f2bf(v0.z); o.y = f2bf(v1.z); o.z = f2bf(v2.z); o.w = f2bf(v3.z);
      *(ushort4*)(base + 528) = o;
      o.x = f2bf(v0.w); o.y = f2bf(v1.w); o.z = f2bf(v2.w); o.w = f2bf(v3.w);
      *(ushort4*)(base + 792) = o;
    }
    __syncthreads();
    {
      int g2 = t >> 4, j = t & 15;        // 16 row-groups x 16 chunks
#pragma unroll
      for (int rr = 0; rr < 8; ++rr) {
        int nl = rr * 16 + g2;
        int n = tn * 128 + nl;
        int orow = (mode == 0) ? n : ((n >> 7) * 256 + ((mode == 2) ? 128 : 0) + (n & 127));
        const char* p = shm + (size_t)nl * 264 + j * 16;
        unsigned long long lo = *(const unsigned long long*)p;
        unsigned long long hi = *(const unsigned long long*)(p + 8);
        uint4 v;
        v.x = (unsigned)lo; v.y = (unsigned)(lo >> 32);
        v.z = (unsigned)hi; v.w = (unsigned)(hi >> 32);
        *(uint4*)(a.dst[z] + (size_t)orow * K + tk * 128 + j * 8) = v;
      }
    }
  }
}

// ---------------- k_addbrms: 4-partial sum + resid + rms (+ next low) -----
template<bool LOW>
__global__ __launch_bounds__(256) void k_addbrms(const float* parts, const float* resid,
                                                 const float* sc, float* resout,
                                                 unsigned short* xn,
                                                 const float* aP, unsigned short* lowext) {
  __shared__ unsigned short lrows[8][1024];
  __shared__ float pacc[8 * 8 * 32];
  __shared__ float red[4];
  const size_t PART = (size_t)2048 * 1024;
  int t = threadIdx.x;
  int row0 = blockIdx.x * 8;
  int b = row0 >> 9;
  float4 s4 = ((const float4*)sc)[t];
  for (int j = 0; j < 8; ++j) {
    int row = row0 + j;
    const float* p0 = parts + (size_t)row * 1024;
    float4 v = ((const float4*)p0)[t];
    float4 v1 = ((const float4*)(p0 + PART))[t];
    float4 v2 = ((const float4*)(p0 + 2 * PART))[t];
    float4 v3 = ((const float4*)(p0 + 3 * PART))[t];
    float4 rv = ((const float4*)(resid + (size_t)row * 1024))[t];
    float4 s;
    s.x = v.x + v1.x + v2.x + v3.x + rv.x;
    s.y = v.y + v1.y + v2.y + v3.y + rv.y;
    s.z = v.z + v1.z + v2.z + v3.z + rv.z;
    s.w = v.w + v1.w + v2.w + v3.w + rv.w;
    ((float4*)(resout + (size_t)row * 1024))[t] = s;
    float ss = s.x * s.x + s.y * s.y + s.z * s.z + s.w * s.w;
    for (int o = 32; o; o >>= 1) ss += __shfl_down(ss, o);
    if ((t & 63) == 0) red[t >> 6] = ss;
    __syncthreads();
    float tot = red[0] + red[1] + red[2] + red[3];
    float rs = rsqrtf(tot * (1.0f / 1024.0f) + 1e-6f);
    ushort4 o;
    o.x = f2bf(s.x * rs * s4.x); o.y = f2bf(s.y * rs * s4.y);
    o.z = f2bf(s.z * rs * s4.z); o.w = f2bf(s.w * rs * s4.w);
    ((ushort4*)(xn + (size_t)row * 1024))[t] = o;
    if (LOW) *(ushort4*)(&lrows[j][t * 4]) = o;
    __syncthreads();
  }
  if (LOW) {
    int r = t & 31, g = t >> 5;
    float acc[8];
#pragma unroll
    for (int j = 0; j < 8; ++j) acc[j] = 0.f;
    const float* ap = aP + (size_t)b * 65536;
    for (int i = 0; i < 128; ++i) {
      int k = g * 128 + i;
      float a0 = ap[(size_t)k * 32 + r];
#pragma unroll
      for (int j = 0; j < 8; ++j) acc[j] += bf2f(lrows[j][k]) * a0;
    }
#pragma unroll
    for (int j = 0; j < 8; ++j) pacc[(j * 8 + g) * 32 + r] = acc[j];
    __syncthreads();
    for (int j = 0; j < 8; ++j) {
      if (t < 32) {
        float s = 0.f;
        for (int gg = 0; gg < 8; ++gg) s += pacc[(j * 8 + gg) * 32 + t];
        lowext[(size_t)(row0 + j) * 128 + t] = f2bf(s);
      } else if (t < 128) {
        lowext[(size_t)(row0 + j) * 128 + t] = 0;
      }
    }
  }
}

// ---------------- low for out-proj (ctx bf16 -> lowext bf16) --------------
__global__ __launch_bounds__(256) void k_lowbf(const unsigned short* x, const float* a,
                                               unsigned short* lowext) {
  int row0 = blockIdx.x * 8;
  int b = row0 >> 9;
  int t = threadIdx.x, r = t & 31, j = t >> 5;
  int row = row0 + j;
  const bf16x8* xv = (const bf16x8*)(x + (size_t)row * 1024);
  const float* ap = a + (size_t)b * 65536;
  float s = 0.f;
  for (int kb = 0; kb < 128; ++kb) {
    bf16x8 v = xv[kb];
#pragma unroll
    for (int u = 0; u < 8; ++u)
      s += (float)v[u] * ap[(size_t)(kb * 8 + u) * 32 + r];
  }
  lowext[(size_t)row * 128 + r] = f2bf(s);
  lowext[(size_t)row * 128 + 32 + r] = 0;
  lowext[(size_t)row * 128 + 64 + r] = 0;
  lowext[(size_t)row * 128 + 96 + r] = 0;
}

// ---------------- final sum ----------------
__global__ void k_sum4(const float* p, size_t pstride, const float* resid, float* out) {
  int i = blockIdx.x * 256 + threadIdx.x;
  float4 a = ((const float4*)p)[i];
  float4 b = ((const float4*)(p + pstride))[i];
  float4 c = ((const float4*)(p + 2 * pstride))[i];
  float4 d = ((const float4*)(p + 3 * pstride))[i];
  float4 r = ((const float4*)resid)[i];
  float4 o;
  o.x = a.x + b.x + c.x + d.x + r.x;
  o.y = a.y + b.y + c.y + d.y + r.y;
  o.z = a.z + b.z + c.z + d.z + r.z;
  o.w = a.w + b.w + c.w + d.w + r.w;
  ((float4*)out)[i] = o;
}

// ---------------------------------------------------------------------------

extern "C" void kernel_launch(void* const* d_in, const int* in_sizes, int n_in,
                              void* d_out, int out_size, void* d_ws, size_t ws_size,
                              hipStream_t stream) {
  const float* f_inputs  = (const float*)d_in[0];
  const float* f_encoded = (const float*)d_in[1];
  const float* f_qa = (const float*)d_in[2];
  const float* f_qb = (const float*)d_in[3];
  const float* f_ka = (const float*)d_in[4];
  const float* f_kb = (const float*)d_in[5];
  const float* f_va = (const float*)d_in[6];
  const float* f_vb = (const float*)d_in[7];
  const float* f_oa = (const float*)d_in[8];
  const float* f_ob = (const float*)d_in[9];
  const float* f_table = (const float*)d_in[10];
  const float* f_ln1 = (const float*)d_in[11];
  const float* f_ln2 = (const float*)d_in[12];
  const float* f_ln3 = (const float*)d_in[13];
  const float* f_W[8] = { (const float*)d_in[14], (const float*)d_in[15],
                          (const float*)d_in[16], (const float*)d_in[17],
                          (const float*)d_in[18], (const float*)d_in[19],
                          (const float*)d_in[20], (const float*)d_in[21] };
  const float* f_wi0 = (const float*)d_in[22];
  const float* f_wi1 = (const float*)d_in[23];
  const float* f_wo  = (const float*)d_in[24];

  const size_t SEL1 = 32768;
  const size_t PART = (size_t)2048 * 1024;

  char* w = (char*)d_ws;
  size_t off = 0;
  auto alloc = [&](size_t bytes) -> char* {
    off = (off + 255) & ~(size_t)255;
    char* p = w + off;
    off += bytes;
    return p;
  };
  unsigned short* wt  = (unsigned short*)alloc((size_t)8192 * 1024 * 2); // q,k,v,o,cq,ck,cv,co
  unsigned short* wc  = (unsigned short*)alloc((size_t)8192 * 1024 * 2); // interleaved wi0/wi1
  unsigned short* wot = (unsigned short*)alloc((size_t)1024 * 4096 * 2);
  unsigned short* encbf = (unsigned short*)alloc(2048 * 1024 * 2);
  float* rb = (float*)alloc(16 * 512 * 4);
  unsigned short* xn  = (unsigned short*)alloc(2048 * 1024 * 2);
  unsigned short* qbf = (unsigned short*)alloc(2048 * 1024 * 2);
  unsigned short* kbf = (unsigned short*)alloc(2048 * 1024 * 2);
  unsigned short* vtb = (unsigned short*)alloc((size_t)64 * 64 * 512 * 2);
  unsigned short* kbf2 = (unsigned short*)alloc(2048 * 1024 * 2);
  unsigned short* vtb2 = (unsigned short*)alloc((size_t)64 * 64 * 512 * 2);
  unsigned short* lowext_s = (unsigned short*)alloc(2048 * 128 * 2);
  unsigned short* lowext_c = (unsigned short*)alloc(2048 * 128 * 2);
  unsigned short* lowext_q = (unsigned short*)alloc(2048 * 128 * 2);
  unsigned short* lowext_o = (unsigned short*)alloc(2048 * 128 * 2);
  unsigned short* bmext_s  = (unsigned short*)alloc((size_t)4 * 3072 * 128 * 2);
  unsigned short* bmext_c  = (unsigned short*)alloc((size_t)4 * 2048 * 128 * 2);
  unsigned short* bmext_q  = (unsigned short*)alloc((size_t)4 * 1024 * 128 * 2);
  unsigned short* bmext_o  = (unsigned short*)alloc((size_t)4 * 1024 * 128 * 2);
  unsigned short* bmext_o2 = (unsigned short*)alloc((size_t)4 * 1024 * 128 * 2);
  unsigned short* ctxb = (unsigned short*)alloc(2048 * 1024 * 2);
  float* xres = (float*)alloc(2048 * 1024 * 4);
  float* yres = (float*)alloc(2048 * 1024 * 4);
  char*  big  = alloc((size_t)84 << 20);
  // big aliases (stream-serial lifetimes):
  float* op_s = (float*)big;                           // self out-proj partials 4x8 MB
  float* qp_c = (float*)(big + ((size_t)32 << 20));    // cross-Q partials 4x8 MB
  float* op_c = (float*)big;                           // cross out-proj partials 4x8 MB
  unsigned short* hbf = (unsigned short*)big;          // 16 MB
  float* fp   = (float*)(big + ((size_t)16 << 20));    // final partials 4x8 MB
  (void)ws_size; (void)in_sizes; (void)n_in; (void)out_size;

  // ---- mega prep ----
  PrepArgs pa;
  int ts = 0;
  for (int i = 0; i < 8; ++i) {
    pa.src[i] = f_W[i]; pa.dst[i] = wt + (size_t)i * 1024 * 1024;
    pa.K[i] = 1024; pa.N[i] = 1024; pa.mode[i] = 0;
    pa.tstart[i] = ts; ts += 64;                      // (1024/128)^2
  }
  pa.src[8] = f_wi0; pa.dst[8] = wc; pa.K[8] = 1024; pa.N[8] = 4096; pa.mode[8] = 1;
  pa.tstart[8] = ts; ts += 256;                       // 8 x 32
  pa.src[9] = f_wi1; pa.dst[9] = wc; pa.K[9] = 1024; pa.N[9] = 4096; pa.mode[9] = 2;
  pa.tstart[9] = ts; ts += 256;
  pa.src[10] = f_wo; pa.dst[10] = wot; pa.K[10] = 4096; pa.N[10] = 1024; pa.mode[10] = 0;
  pa.tstart[10] = ts; ts += 256;                      // 32 x 8
  pa.tstart[11] = ts;
  pa.nwt = ts;
  pa.encoded = f_encoded; pa.encbf = encbf;
  pa.table = f_table; pa.rb = rb;
  pa.nf2bf = 256;
  pa.bmdst[0] = bmext_s;  pa.bmnrg[0] = 24;
  pa.bmsrc[0][0] = f_qb; pa.bmsrc[0][1] = f_kb; pa.bmsrc[0][2] = f_vb;
  pa.bmdst[1] = bmext_c;  pa.bmnrg[1] = 16;
  pa.bmsrc[1][0] = f_kb + SEL1; pa.bmsrc[1][1] = f_vb + SEL1; pa.bmsrc[1][2] = nullptr;
  pa.bmdst[2] = bmext_q;  pa.bmnrg[2] = 8;
  pa.bmsrc[2][0] = f_qb + SEL1; pa.bmsrc[2][1] = nullptr; pa.bmsrc[2][2] = nullptr;
  pa.bmdst[3] = bmext_o;  pa.bmnrg[3] = 8;
  pa.bmsrc[3][0] = f_ob; pa.bmsrc[3][1] = nullptr; pa.bmsrc[3][2] = nullptr;
  pa.bmdst[4] = bmext_o2; pa.bmnrg[4] = 8;
  pa.bmsrc[4][0] = f_ob + SEL1; pa.bmsrc[4][1] = nullptr; pa.bmsrc[4][2] = nullptr;
  int bs = 0;
  for (int m = 0; m < 5; ++m) { pa.bmstart[m] = bs; bs += pa.bmnrg[m] * 4; }
  pa.bmstart[5] = bs;
  pa.nbm = bs;
  pa.xin = f_inputs; pa.ln1 = f_ln1;
  pa.qa = f_qa; pa.ka = f_ka; pa.va = f_va;
  pa.xnp = xn; pa.lows = lowext_s;
  pa.lca0 = f_ka + SEL1; pa.lca1 = f_va + SEL1;
  pa.lowc = lowext_c;
  int totblk = 512 + pa.nbm + 32 + pa.nf2bf + pa.nwt;
  k_prep<<<dim3(totblk), dim3(256), 0, stream>>>(pa);

  // ---- big QKV fused: self (N=3072) + crossKV (N=2048), bf16 out + Vt ----
  {
    QKV2 g;
    g.s[0] = { xn, lowext_s, wt, bmext_s,
               qbf, kbf, vtb, (size_t)3072 * 128, 2, 24 };
    g.s[1] = { encbf, lowext_c, wt + (size_t)5120 * 1024, bmext_c,
               kbf2, vtb2, nullptr, (size_t)2048 * 128, 1, 16 };
    k_gemmqkv<<<dim3(24, 16, 2), dim3(256), 0, stream>>>(g);
  }

  k_flash<true, false><<<dim3(8, 64), dim3(256), 0, stream>>>(qbf, nullptr, kbf, vtb, rb, ctxb);

  // ---- self out-proj (K-ext lora_o, S4) ----
  k_lowbf<<<dim3(256), dim3(256), 0, stream>>>(ctxb, f_oa, lowext_o);
  {
    GX g;
    for (int s = 0; s < 4; ++s)
      g.s[s] = { ctxb, lowext_o, wt + (size_t)3072 * 1024, bmext_o, op_s + (size_t)s * PART,
                 (size_t)1024 * 128, 1024, 8, s * 18 / 4, (s + 1) * 18 / 4 };
    k_gemmx<<<dim3(8, 16, 4), dim3(256), 0, stream>>>(g);
  }
  k_addbrms<true><<<dim3(256), dim3(256), 0, stream>>>(op_s, f_inputs, f_ln2, xres, xn,
                                                       f_qa + SEL1, lowext_q);

  // ---- cross-Q (K-ext, S4) ----
  {
    GX g;
    for (int s = 0; s < 4; ++s)
      g.s[s] = { xn, lowext_q, wt + (size_t)4096 * 1024, bmext_q, qp_c + (size_t)s * PART,
                 (size_t)1024 * 128, 1024, 8, s * 18 / 4, (s + 1) * 18 / 4 };
    k_gemmx<<<dim3(8, 16, 4), dim3(256), 0, stream>>>(g);
  }
  k_flash<false, true><<<dim3(8, 64), dim3(256), 0, stream>>>(nullptr, qp_c, kbf2, vtb2, rb, ctxb);

  // ---- cross out-proj (K-ext lora_o sel1, S4) ----
  k_lowbf<<<dim3(256), dim3(256), 0, stream>>>(ctxb, f_oa + SEL1, lowext_o);
  {
    GX g;
    for (int s = 0; s < 4; ++s)
      g.s[s] = { ctxb, lowext_o, wt + (size_t)7168 * 1024, bmext_o2, op_c + (size_t)s * PART,
                 (size_t)1024 * 128, 1024, 8, s * 18 / 4, (s + 1) * 18 / 4 };
    k_gemmx<<<dim3(8, 16, 4), dim3(256), 0, stream>>>(g);
  }
  k_addbrms<false><<<dim3(256), dim3(256), 0, stream>>>(op_c, xres, f_ln3, yres, xn,
                                                        nullptr, nullptr);

  // ---- MLP ----
  k_mlp<<<dim3(32, 16), dim3(512), 0, stream>>>(xn, wc, hbf);
  k_gemm1s<<<dim3(8, 16, 4), dim3(256), 0, stream>>>(hbf, wot, fp, PART, 1024, 4096, 4096, 1024);
  k_sum4<<<dim3(2048), dim3(256), 0, stream>>>(fp, PART, yres, (float*)d_out);
}

// Round 10
// 506.946 us; speedup vs baseline: 1.0937x; 1.0014x over previous
//
#include <hip/hip_runtime.h>
#include <math.h>

// ---------------------------------------------------------------------------
// LoRA T5 decoder layer on MI355X (gfx950).
// B=4, L=ENC=512, D=1024, H=16, HD=64, MLP=4096, R=32.
// R19 resubmit (R9 bench was an infra failure, no counters).
// R18->R19: second application of "hide streams under other kernels".
// 960 of k_prep's 1280 transpose blocks produce weights consumed only after
// the QKV GEMM (Wo, cWq, cWo, wi0, wi1, wo ~ 90MB logical traffic). Moved
// into k_gemmqkv as grid.z slices 2..4 (latency-bound GEMM @1.4TB/s, 17%
// MfmaUtil, 4 blocks/CU capacity vs 768 launched -> transposes co-reside).
// k_prep keeps q,k,v,ck,cv transposes + start/lowc/bmext/relbias/encbf.
// ---------------------------------------------------------------------------

#define DEV __device__ __forceinline__

typedef __bf16 bf16x8 __attribute__((ext_vector_type(8)));
typedef float floatx4 __attribute__((ext_vector_type(4)));

typedef __attribute__((address_space(1))) void* gas_ptr;
typedef __attribute__((address_space(3))) void* las_ptr;

DEV unsigned short f2bf(float f) {
  union { float f; unsigned int u; } v; v.f = f;
  unsigned int r = v.u + 0x7fffu + ((v.u >> 16) & 1u);
  return (unsigned short)(r >> 16);
}
DEV float bf2f(unsigned short u) {
  union { unsigned int u; float f; } v; v.u = ((unsigned int)u) << 16;
  return v.f;
}

#define GLOAD_LDS16(g, l) __builtin_amdgcn_global_load_lds((gas_ptr)(g), (las_ptr)(l), 16, 0, 0)

// Swizzled staging, 128B rows: LDS physical chunk-col p of row r holds logical
// chunk (p ^ (r&7)). Lane p=(lane&7), r&7=(lane>>3)&7 -> load logical col
// (lane&7)^((lane>>3)&7). Same 128-B segments per wave => coalescing kept.
template<int NW>
DEV void stage_tile_sw(const char* gbase, char* lds, int nrows, int ldbytes, int wave, int lane) {
  int nchunks = nrows >> 3;
  int colb = (((lane & 7) ^ ((lane >> 3) & 7)) << 4);
  for (int c = wave; c < nchunks; c += NW) {
    int row = (c << 3) + (lane >> 3);
    GLOAD_LDS16(gbase + (size_t)row * ldbytes + colb, lds + (c << 10));
  }
}

// Swizzled staging, 256B rows (16 chunks/row): phys chunk p of row r holds
// logical (p ^ (r&7)). Here r&7 depends on c parity: r = (c<<2)+(lane>>4).
template<int NW>
DEV void stage_tile256_sw(const char* gbase, char* lds, int nrows, int ldbytes, int wave, int lane) {
  int nchunks = nrows >> 2;
  for (int c = wave; c < nchunks; c += NW) {
    int row = (c << 2) + (lane >> 4);
    int key = row & 7;
    int colb = ((lane & 15) ^ key) << 4;
    GLOAD_LDS16(gbase + (size_t)row * ldbytes + colb, lds + (c << 10));
  }
}

// ---- shared 128x128 fp32->bf16 transpose tile (33792B LDS required) ------
DEV void transpose_tile128(const float* src0, unsigned short* dst,
                           int N, int K, int mode, int tn, int tk,
                           char* shm, int t) {
  const float* src = src0 + (size_t)(tk * 128) * N + tn * 128;
#pragma unroll
  for (int i = 0; i < 4; ++i) {
    int c = i * 256 + t;                // 0..1023
    int k4 = c >> 5;                    // 0..31 (k0 = k4*4)
    int c4 = c & 31;                    // col4 (n0 = c4*4)
    const float* p = src + (size_t)(k4 * 4) * N + c4 * 4;
    float4 v0 = *(const float4*)(p);
    float4 v1 = *(const float4*)(p + N);
    float4 v2 = *(const float4*)(p + 2 * (size_t)N);
    float4 v3 = *(const float4*)(p + 3 * (size_t)N);
    char* base = shm + (size_t)(c4 * 4) * 264 + k4 * 8;
    ushort4 o;
    o.x = f2bf(v0.x); o.y = f2bf(v1.x); o.z = f2bf(v2.x); o.w = f2bf(v3.x);
    *(ushort4*)(base) = o;
    o.x = f2bf(v0.y); o.y = f2bf(v1.y); o.z = f2bf(v2.y); o.w = f2bf(v3.y);
    *(ushort4*)(base + 264) = o;
    o.x = f2bf(v0.z); o.y = f2bf(v1.z); o.z = f2bf(v2.z); o.w = f2bf(v3.z);
    *(ushort4*)(base + 528) = o;
    o.x = f2bf(v0.w); o.y = f2bf(v1.w); o.z = f2bf(v2.w); o.w = f2bf(v3.w);
    *(ushort4*)(base + 792) = o;
  }
  __syncthreads();
  {
    int g2 = t >> 4, j = t & 15;        // 16 row-groups x 16 chunks
#pragma unroll
    for (int rr = 0; rr < 8; ++rr) {
      int nl = rr * 16 + g2;
      int n = tn * 128 + nl;
      int orow = (mode == 0) ? n : ((n >> 7) * 256 + ((mode == 2) ? 128 : 0) + (n & 127));
      const char* p = shm + (size_t)nl * 264 + j * 16;
      unsigned long long lo = *(const unsigned long long*)p;
      unsigned long long hi = *(const unsigned long long*)(p + 8);
      uint4 v;
      v.x = (unsigned)lo; v.y = (unsigned)(lo >> 32);
      v.z = (unsigned)hi; v.w = (unsigned)(hi >> 32);
      *(uint4*)(dst + (size_t)orow * K + tk * 128 + j * 8) = v;
    }
  }
}

// ---------------- generic bf16 GEMM core (fp32 out), 128x128 tile ----------
// Swizzled LDS: fragment read col16 = ((kk>>3)+quad) ^ (l15&7).
template<int WM, int WN>
DEV void gemm_core(const unsigned short* A, const unsigned short* Bt, float* C,
                   int K, int lda, int ldb, int ldc, int m0, int n0,
                   char* ldsA, char* ldsB) {
  constexpr int NW = WM * WN;
  const int tid  = threadIdx.x;
  const int lane = tid & 63;
  const int wave = tid >> 6;
  const int wm   = wave % WM;
  const int wn   = wave / WM;
  const int quad = lane >> 4;
  const int l15  = lane & 15;
  const int key  = l15 & 7;

  floatx4 acc[4][4];
#pragma unroll
  for (int i = 0; i < 4; ++i)
#pragma unroll
    for (int j = 0; j < 4; ++j) acc[i][j] = (floatx4){0.f, 0.f, 0.f, 0.f};

  const char* gA = (const char*)(A + (size_t)m0 * lda);
  const char* gB = (const char*)(Bt + (size_t)n0 * ldb);

  for (int k0 = 0; k0 < K; k0 += 64) {
    stage_tile_sw<NW>(gA + (size_t)k0 * 2, ldsA, WM * 64, lda * 2, wave, lane);
    stage_tile_sw<NW>(gB + (size_t)k0 * 2, ldsB, WN * 64, ldb * 2, wave, lane);
    __syncthreads();
#pragma unroll
    for (int kk = 0; kk < 64; kk += 32) {
      bf16x8 af[4], bv[4];
      int off = (((kk >> 3) + quad) ^ key) << 4;
      const char* baseA = ldsA + (size_t)(wm * 64 + l15) * 128 + off;
      const char* baseB = ldsB + (size_t)(wn * 64 + l15) * 128 + off;
#pragma unroll
      for (int mi = 0; mi < 4; ++mi) af[mi] = *(const bf16x8*)(baseA + mi * 2048);
#pragma unroll
      for (int ni = 0; ni < 4; ++ni) bv[ni] = *(const bf16x8*)(baseB + ni * 2048);
#pragma unroll
      for (int mi = 0; mi < 4; ++mi)
#pragma unroll
        for (int ni = 0; ni < 4; ++ni)
          acc[mi][ni] = __builtin_amdgcn_mfma_f32_16x16x32_bf16(af[mi], bv[ni], acc[mi][ni], 0, 0, 0);
    }
    __syncthreads();
  }

#pragma unroll
  for (int mi = 0; mi < 4; ++mi) {
#pragma unroll
    for (int r = 0; r < 4; ++r) {
      int row = m0 + wm * 64 + mi * 16 + quad * 4 + r;
#pragma unroll
      for (int ni = 0; ni < 4; ++ni) {
        int col = n0 + wn * 64 + ni * 16 + l15;
        C[(size_t)row * ldc + col] = acc[mi][ni][r];
      }
    }
  }
}

__global__ __launch_bounds__(256) void k_gemm1s(const unsigned short* A, const unsigned short* Bt,
                                                float* Cpart, size_t pstride,
                                                int Kchunk, int lda, int ldb, int ldc) {
  __shared__ char lds[32768];
  int s = blockIdx.z;
  size_t koff = (size_t)s * Kchunk;
  gemm_core<2, 2>(A + koff, Bt + koff, Cpart + (size_t)s * pstride,
                  Kchunk, lda, ldb, ldc,
                  blockIdx.y * 128, blockIdx.x * 128, lds, lds + 16384);
}

// ---------------- K-extended GEMM: C = [A0|Aext] @ [B0|Bext(b)]^T ----------
struct GXSlice {
  const unsigned short* A0;
  const unsigned short* Aext;
  const unsigned short* B0;
  const unsigned short* Bext;
  float* C;
  size_t bextb;            // per-b element stride of Bext (= N*128)
  int ldc, nxa, it0, it1;
};
struct GX { GXSlice s[4]; };

__global__ __launch_bounds__(256) void k_gemmx(GX g) {
  __shared__ char lds[32768];
  char* ldsA = lds;
  char* ldsB = lds + 16384;
  GXSlice sl = g.s[blockIdx.z];
  if ((int)blockIdx.x >= sl.nxa) return;
  const int m0 = blockIdx.y * 128, n0 = blockIdx.x * 128;
  const int b = m0 >> 9;
  const int tid = threadIdx.x, lane = tid & 63, wave = tid >> 6;
  const int wm = wave & 1, wn = wave >> 1;
  const int quad = lane >> 4, l15 = lane & 15;
  const int key = l15 & 7;

  floatx4 acc[4][4];
#pragma unroll
  for (int i = 0; i < 4; ++i)
#pragma unroll
    for (int j = 0; j < 4; ++j) acc[i][j] = (floatx4){0.f, 0.f, 0.f, 0.f};

  for (int it = sl.it0; it < sl.it1; ++it) {
    if (it < 16) {
      stage_tile_sw<4>((const char*)sl.A0 + (size_t)m0 * 2048 + it * 128, ldsA, 128, 2048, wave, lane);
      stage_tile_sw<4>((const char*)sl.B0 + (size_t)n0 * 2048 + it * 128, ldsB, 128, 2048, wave, lane);
    } else {
      int eb = (it - 16) * 128;
      stage_tile_sw<4>((const char*)sl.Aext + (size_t)m0 * 256 + eb, ldsA, 128, 256, wave, lane);
      stage_tile_sw<4>((const char*)(sl.Bext + (size_t)b * sl.bextb) + (size_t)n0 * 256 + eb,
                       ldsB, 128, 256, wave, lane);
    }
    __syncthreads();
#pragma unroll
    for (int kk = 0; kk < 64; kk += 32) {
      bf16x8 af[4], bv[4];
      int off = (((kk >> 3) + quad) ^ key) << 4;
      const char* baseA = ldsA + (size_t)(wm * 64 + l15) * 128 + off;
      const char* baseB = ldsB + (size_t)(wn * 64 + l15) * 128 + off;
#pragma unroll
      for (int mi = 0; mi < 4; ++mi) af[mi] = *(const bf16x8*)(baseA + mi * 2048);
#pragma unroll
      for (int ni = 0; ni < 4; ++ni) bv[ni] = *(const bf16x8*)(baseB + ni * 2048);
#pragma unroll
      for (int mi = 0; mi < 4; ++mi)
#pragma unroll
        for (int ni = 0; ni < 4; ++ni)
          acc[mi][ni] = __builtin_amdgcn_mfma_f32_16x16x32_bf16(af[mi], bv[ni], acc[mi][ni], 0, 0, 0);
    }
    __syncthreads();
  }

#pragma unroll
  for (int mi = 0; mi < 4; ++mi) {
#pragma unroll
    for (int r = 0; r < 4; ++r) {
      int row = m0 + wm * 64 + mi * 16 + quad * 4 + r;
#pragma unroll
      for (int ni = 0; ni < 4; ++ni) {
        int col = n0 + wn * 64 + ni * 16 + l15;
        sl.C[(size_t)row * sl.ldc + col] = acc[mi][ni][r];
      }
    }
  }
}

// ---------------- fused QKV GEMM + late-weight transposes -----------------
// z<2: GEMM C = [A0|Aext] @ [B0|Bext(b)]^T (18 iters), bf16 epilogue,
//      in-LDS V transpose for section vsec.
// z>=2: 128x128 weight transpose tiles (Wo,cWq,cWo,wi0,wi1,wo), consumed
//      only by later kernels (stream-serial => safe).
struct QKVSlice {
  const unsigned short* A0;
  const unsigned short* Aext;
  const unsigned short* B0;
  const unsigned short* Bext;
  unsigned short* sec0;
  unsigned short* sec1;
  unsigned short* sec2;
  size_t bextb;
  int vsec, nxa;
};
struct QKVT {
  QKVSlice s[2];
  const float* tsrc[6];
  unsigned short* tdst[6];
  int tK[6], tN[6], tmode[6];
  int tstart[7];
  int ntt;
};

__global__ __launch_bounds__(256) void k_gemmqkv(QKVT g) {
  __shared__ char lds[34816];          // 32KB staging; also 33.8KB transpose
  char* ldsA = lds;
  char* ldsB = lds + 16384;
  const int tid = threadIdx.x;
  if (blockIdx.z >= 2) {
    int bid = (blockIdx.z - 2) * 384 + blockIdx.y * 24 + blockIdx.x;
    if (bid >= g.ntt) return;
    int z = 0;
    while (z < 5 && bid >= g.tstart[z + 1]) ++z;
    int tile = bid - g.tstart[z];
    int N = g.tN[z], K = g.tK[z];
    int ntn = N >> 7;
    transpose_tile128(g.tsrc[z], g.tdst[z], N, K, g.tmode[z],
                      tile % ntn, tile / ntn, lds, tid);
    return;
  }
  QKVSlice sl = g.s[blockIdx.z];
  if ((int)blockIdx.x >= sl.nxa) return;
  const int m0 = blockIdx.y * 128, n0 = blockIdx.x * 128;
  const int b = m0 >> 9;
  const int lane = tid & 63, wave = tid >> 6;
  const int wm = wave & 1, wn = wave >> 1;
  const int quad = lane >> 4, l15 = lane & 15;
  const int key = l15 & 7;

  floatx4 acc[4][4];
#pragma unroll
  for (int i = 0; i < 4; ++i)
#pragma unroll
    for (int j = 0; j < 4; ++j) acc[i][j] = (floatx4){0.f, 0.f, 0.f, 0.f};

  for (int it = 0; it < 18; ++it) {
    if (it < 16) {
      stage_tile_sw<4>((const char*)sl.A0 + (size_t)m0 * 2048 + it * 128, ldsA, 128, 2048, wave, lane);
      stage_tile_sw<4>((const char*)sl.B0 + (size_t)n0 * 2048 + it * 128, ldsB, 128, 2048, wave, lane);
    } else {
      int eb = (it - 16) * 128;
      stage_tile_sw<4>((const char*)sl.Aext + (size_t)m0 * 256 + eb, ldsA, 128, 256, wave, lane);
      stage_tile_sw<4>((const char*)(sl.Bext + (size_t)b * sl.bextb) + (size_t)n0 * 256 + eb,
                       ldsB, 128, 256, wave, lane);
    }
    __syncthreads();
#pragma unroll
    for (int kk = 0; kk < 64; kk += 32) {
      bf16x8 af[4], bv[4];
      int off = (((kk >> 3) + quad) ^ key) << 4;
      const char* baseA = ldsA + (size_t)(wm * 64 + l15) * 128 + off;
      const char* baseB = ldsB + (size_t)(wn * 64 + l15) * 128 + off;
#pragma unroll
      for (int mi = 0; mi < 4; ++mi) af[mi] = *(const bf16x8*)(baseA + mi * 2048);
#pragma unroll
      for (int ni = 0; ni < 4; ++ni) bv[ni] = *(const bf16x8*)(baseB + ni * 2048);
#pragma unroll
      for (int mi = 0; mi < 4; ++mi)
#pragma unroll
        for (int ni = 0; ni < 4; ++ni)
          acc[mi][ni] = __builtin_amdgcn_mfma_f32_16x16x32_bf16(af[mi], bv[ni], acc[mi][ni], 0, 0, 0);
    }
    __syncthreads();
  }

  const int sec = n0 >> 10;
  const int nloc = n0 & 1023;
  if (sec != sl.vsec) {
    // row-major bf16 store (q or k section)
    unsigned short* dst = (sec == 0) ? sl.sec0 : sl.sec1;
#pragma unroll
    for (int mi = 0; mi < 4; ++mi)
#pragma unroll
      for (int r = 0; r < 4; ++r) {
        int row = m0 + wm * 64 + mi * 16 + quad * 4 + r;
        unsigned short* drow = dst + (size_t)row * 1024 + nloc + wn * 64;
#pragma unroll
        for (int ni = 0; ni < 4; ++ni)
          drow[ni * 16 + l15] = f2bf(acc[mi][ni][r]);
      }
  } else {
    // V section: per-wave 64x64 transpose via LDS (staging LDS is free here).
    unsigned short* vdstb = (sl.vsec == 1) ? sl.sec1 : sl.sec2;
    char* vbuf = lds + (size_t)(wm * 2 + wn) * 8704;   // [64 d][136B] (68 elem rows)
#pragma unroll
    for (int ni = 0; ni < 4; ++ni)
#pragma unroll
      for (int mi = 0; mi < 4; ++mi) {
        unsigned long long pk =
            (unsigned long long)f2bf(acc[mi][ni][0])
          | ((unsigned long long)f2bf(acc[mi][ni][1]) << 16)
          | ((unsigned long long)f2bf(acc[mi][ni][2]) << 32)
          | ((unsigned long long)f2bf(acc[mi][ni][3]) << 48);
        *(unsigned long long*)(vbuf + (size_t)(ni * 16 + l15) * 136 + (mi * 16 + quad * 4) * 2) = pk;
      }
    __syncthreads();
    int dbase = nloc + wn * 64;        // multiple of 64 -> one head per wave
    int h = dbase >> 6;
    int kb = (m0 & 511) + wm * 64;
    unsigned short* vdst = vdstb + (size_t)(b * 16 + h) * 64 * 512;
    int lh = lane >> 3, ll = lane & 7;
#pragma unroll
    for (int i = 0; i < 8; ++i) {
      int d = i * 8 + lh;
      const char* p = vbuf + (size_t)d * 136 + ll * 16;
      unsigned long long lo = *(const unsigned long long*)p;
      unsigned long long hi = *(const unsigned long long*)(p + 8);
      uint4 v;
      v.x = (unsigned)lo; v.y = (unsigned)(lo >> 32);
      v.z = (unsigned)hi; v.w = (unsigned)(hi >> 32);
      *(uint4*)(vdst + (size_t)d * 512 + kb + ll * 8) = v;
    }
  }
}

// ---------------- flash attention (XOR-swizzled LDS) ----------------------
template<bool CAUSAL, bool QSUM>
__global__ __launch_bounds__(256) void k_flash(const unsigned short* qmat, const float* qparts,
                                               const unsigned short* kmat, const unsigned short* vt,
                                               const float* rb, unsigned short* ctxb) {
  __shared__ char ldsQ[8192];    // [64 q][64 d]
  __shared__ char ldsK[16384];   // [128 k][64 d]
  __shared__ char ldsV[16384];   // [64 d][128 k]
  __shared__ char ldsP[16384];   // [64 q][128 k]
  __shared__ float lrb[512];

  const size_t PART = (size_t)2048 * 1024;
  const int z = blockIdx.y, b = z >> 4, h = z & 15;
  const int q0 = blockIdx.x * 64;
  const int tid = threadIdx.x, lane = tid & 63, wave = tid >> 6;
  const int quad = lane >> 4, l15 = lane & 15;
  const int key = l15 & 7;

  const unsigned short* K = kmat + (size_t)b * 512 * 1024 + h * 64;
  const unsigned short* V = vt + (size_t)z * 64 * 512;

  if (QSUM) {
#pragma unroll
    for (int rr = 0; rr < 4; ++rr) {
      int row = rr * 16 + (tid >> 4);
      int c4 = tid & 15;
      const float* src = qparts + (size_t)(q0 + row) * 1024 + h * 64 + c4 * 4;
      float4 s0 = *(const float4*)src;
      float4 s1 = *(const float4*)(src + PART);
      float4 s2 = *(const float4*)(src + 2 * PART);
      float4 s3 = *(const float4*)(src + 3 * PART);
      ushort4 o;
      o.x = f2bf(s0.x + s1.x + s2.x + s3.x);
      o.y = f2bf(s0.y + s1.y + s2.y + s3.y);
      o.z = f2bf(s0.z + s1.z + s2.z + s3.z);
      o.w = f2bf(s0.w + s1.w + s2.w + s3.w);
      // 8B granule: logical chunk = c4>>1, half = c4&1; swizzle the chunk.
      int qoff = (((c4 >> 1) ^ (row & 7)) << 4) | ((c4 & 1) << 3);
      *(ushort4*)(ldsQ + (size_t)row * 128 + qoff) = o;
    }
  } else {
    const unsigned short* Q = qmat + (size_t)b * 512 * 1024 + h * 64;
    stage_tile_sw<4>((const char*)(Q + (size_t)q0 * 1024), ldsQ, 64, 2048, wave, lane);
  }
  if (CAUSAL)
    for (int i = tid; i < 512; i += 256) lrb[i] = rb[h * 512 + i];

  float m_run[4], l_run[4];
  floatx4 oacc[4];
#pragma unroll
  for (int r = 0; r < 4; ++r) { m_run[r] = -1e30f; l_run[r] = 0.f; }
#pragma unroll
  for (int ni = 0; ni < 4; ++ni) oacc[ni] = (floatx4){0.f, 0.f, 0.f, 0.f};

  const int ktend = CAUSAL ? (blockIdx.x / 2 + 1) : 4;
  for (int kt = 0; kt < ktend; ++kt) {
    __syncthreads();
    stage_tile_sw<4>((const char*)(K + (size_t)kt * 128 * 1024), ldsK, 128, 2048, wave, lane);
    stage_tile256_sw<4>((const char*)(V + kt * 128), ldsV, 64, 1024, wave, lane);
    __syncthreads();

    floatx4 sacc[8];
#pragma unroll
    for (int ct = 0; ct < 8; ++ct) sacc[ct] = (floatx4){0.f, 0.f, 0.f, 0.f};
    const size_t qrow = (size_t)(wave * 16 + l15) * 128;
#pragma unroll
    for (int kd = 0; kd < 2; ++kd) {
      int offq = ((quad + kd * 4) ^ key) << 4;
      bf16x8 af = *(const bf16x8*)(ldsQ + qrow + offq);
#pragma unroll
      for (int ct = 0; ct < 8; ++ct) {
        bf16x8 bfv = *(const bf16x8*)(ldsK + (size_t)(ct * 16 + l15) * 128 + offq);
        sacc[ct] = __builtin_amdgcn_mfma_f32_16x16x32_bf16(af, bfv, sacc[ct], 0, 0, 0);
      }
    }

    float sv[8][4];
#pragma unroll
    for (int ct = 0; ct < 8; ++ct)
#pragma unroll
      for (int r = 0; r < 4; ++r) {
        float v = sacc[ct][r] * 0.125f;
        if (CAUSAL) {
          int qq = q0 + wave * 16 + quad * 4 + r;
          int kk = kt * 128 + ct * 16 + l15;
          v = (kk <= qq) ? v + lrb[qq - kk] : -1e30f;
        }
        sv[ct][r] = v;
      }

    float mx[4];
#pragma unroll
    for (int r = 0; r < 4; ++r) {
      mx[r] = sv[0][r];
#pragma unroll
      for (int ct = 1; ct < 8; ++ct) mx[r] = fmaxf(mx[r], sv[ct][r]);
    }
#pragma unroll
    for (int o = 1; o < 16; o <<= 1)
#pragma unroll
      for (int r = 0; r < 4; ++r) mx[r] = fmaxf(mx[r], __shfl_xor(mx[r], o));

    float alpha[4], rs[4];
#pragma unroll
    for (int r = 0; r < 4; ++r) {
      float mn = fmaxf(m_run[r], mx[r]);
      alpha[r] = __expf(m_run[r] - mn);
      m_run[r] = mn;
      rs[r] = 0.f;
    }
#pragma unroll
    for (int ct = 0; ct < 8; ++ct)
#pragma unroll
      for (int r = 0; r < 4; ++r) {
        float p = __expf(sv[ct][r] - m_run[r]);
        sv[ct][r] = p;
        rs[r] += p;
      }
#pragma unroll
    for (int o = 1; o < 16; o <<= 1)
#pragma unroll
      for (int r = 0; r < 4; ++r) rs[r] += __shfl_xor(rs[r], o);
#pragma unroll
    for (int r = 0; r < 4; ++r) l_run[r] = l_run[r] * alpha[r] + rs[r];
#pragma unroll
    for (int ni = 0; ni < 4; ++ni)
#pragma unroll
      for (int r = 0; r < 4; ++r) oacc[ni][r] *= alpha[r];

#pragma unroll
    for (int ct = 0; ct < 8; ++ct)
#pragma unroll
      for (int r = 0; r < 4; ++r) {
        int prow_w = wave * 16 + quad * 4 + r;
        int kidx = ct * 16 + l15;
        int pb = (((kidx >> 3) ^ (prow_w & 7)) << 4) | ((kidx & 7) << 1);
        *(unsigned short*)(ldsP + (size_t)prow_w * 256 + pb) = f2bf(sv[ct][r]);
      }
    __syncthreads();

    const size_t prow = (size_t)(wave * 16 + l15) * 256;
#pragma unroll
    for (int kk = 0; kk < 4; ++kk) {
      int offp = ((quad + kk * 4) ^ key) << 4;
      bf16x8 pf = *(const bf16x8*)(ldsP + prow + offp);
#pragma unroll
      for (int ni = 0; ni < 4; ++ni) {
        bf16x8 vf8 = *(const bf16x8*)(ldsV + (size_t)(ni * 16 + l15) * 256 + offp);
        oacc[ni] = __builtin_amdgcn_mfma_f32_16x16x32_bf16(pf, vf8, oacc[ni], 0, 0, 0);
      }
    }
  }

#pragma unroll
  for (int r = 0; r < 4; ++r) {
    int q = q0 + wave * 16 + quad * 4 + r;
    float inv = 1.0f / l_run[r];
    unsigned short* dst = ctxb + ((size_t)b * 512 + q) * 1024 + h * 64;
#pragma unroll
    for (int ni = 0; ni < 4; ++ni)
      dst[ni * 16 + l15] = f2bf(oacc[ni][r] * inv);
  }
}

// ---------------- fused MLP (swizzled LDS) ----------------
__global__ __launch_bounds__(512) void k_mlp(const unsigned short* A, const unsigned short* Wc,
                                             unsigned short* hbf) {
  __shared__ char lds[49152];
  char* ldsA = lds;
  char* ldsB = lds + 16384;
  const int m0 = blockIdx.y * 128;
  const int n0 = blockIdx.x * 128;
  const int tid = threadIdx.x, lane = tid & 63, wave = tid >> 6;
  const int half = wave >> 2, wl = wave & 3;
  const int wm = wl & 1, wn = wl >> 1;
  const int quad = lane >> 4, l15 = lane & 15;
  const int key = l15 & 7;

  floatx4 acc[4][4];
#pragma unroll
  for (int i = 0; i < 4; ++i)
#pragma unroll
    for (int j = 0; j < 4; ++j) acc[i][j] = (floatx4){0.f, 0.f, 0.f, 0.f};

  const char* gA = (const char*)(A + (size_t)m0 * 1024);
  const char* gB = (const char*)(Wc + (size_t)blockIdx.x * 256 * 1024);

  for (int k0 = 0; k0 < 1024; k0 += 64) {
    stage_tile_sw<8>(gA + (size_t)k0 * 2, ldsA, 128, 2048, wave, lane);
    stage_tile_sw<8>(gB + (size_t)k0 * 2, ldsB, 256, 2048, wave, lane);
    __syncthreads();
#pragma unroll
    for (int kk = 0; kk < 64; kk += 32) {
      bf16x8 af[4], bv[4];
      int off = (((kk >> 3) + quad) ^ key) << 4;
      const char* baseA = ldsA + (size_t)(wm * 64 + l15) * 128 + off;
      const char* baseB = ldsB + (size_t)(half * 128 + wn * 64 + l15) * 128 + off;
#pragma unroll
      for (int mi = 0; mi < 4; ++mi) af[mi] = *(const bf16x8*)(baseA + mi * 2048);
#pragma unroll
      for (int ni = 0; ni < 4; ++ni) bv[ni] = *(const bf16x8*)(baseB + ni * 2048);
#pragma unroll
      for (int mi = 0; mi < 4; ++mi)
#pragma unroll
        for (int ni = 0; ni < 4; ++ni)
          acc[mi][ni] = __builtin_amdgcn_mfma_f32_16x16x32_bf16(af[mi], bv[ni], acc[mi][ni], 0, 0, 0);
    }
    __syncthreads();
  }

  if (half == 1) {
#pragma unroll
    for (int mi = 0; mi < 4; ++mi)
#pragma unroll
      for (int r = 0; r < 4; ++r) {
        int row = wm * 64 + mi * 16 + quad * 4 + r;
#pragma unroll
        for (int ni = 0; ni < 4; ++ni) {
          int col = wn * 64 + ni * 16 + l15;
          *(unsigned short*)(ldsB + (size_t)row * 256 + col * 2) = f2bf(acc[mi][ni][r]);
        }
      }
  }
  __syncthreads();
  if (half == 0) {
#pragma unroll
    for (int mi = 0; mi < 4; ++mi)
#pragma unroll
      for (int r = 0; r < 4; ++r) {
        int row = wm * 64 + mi * 16 + quad * 4 + r;
#pragma unroll
        for (int ni = 0; ni < 4; ++ni) {
          int col = wn * 64 + ni * 16 + l15;
          float h1 = bf2f(*(const unsigned short*)(ldsB + (size_t)row * 256 + col * 2));
          float g = acc[mi][ni][r];
          float v = 0.5f * g * (1.0f + erff(g * 0.70710678f)) * h1;
          hbf[(size_t)(m0 + row) * 4096 + n0 + col] = f2bf(v);
        }
      }
  }
}

// ---------------- mega-prep: start + lowc + bmext + relbias + encbf + T ---
struct PrepArgs {
  const float* src[5];
  unsigned short* dst[5];
  int tstart[6];
  const float* encoded;
  unsigned short* encbf;
  const float* table;
  float* rb;
  unsigned short* bmdst[5];
  const float* bmsrc[5][3];
  int bmnrg[5];
  int bmstart[6];
  int nwt, nf2bf, nbm;
  // fused k_start:
  const float* xin; const float* ln1;
  const float* qa; const float* ka; const float* va;
  unsigned short* xnp; unsigned short* lows;
  // fused k_lowc:
  const float* lca0; const float* lca1;
  unsigned short* lowc;
};
__global__ __launch_bounds__(256, 2) void k_prep(PrepArgs a) {
  __shared__ char shm[33792];
  int bid = blockIdx.x;
  int t = threadIdx.x;
  if (bid < 256) {
    // ---- k_start: rmsnorm + self q/k/v lows (j-split epilogue) ----
    unsigned short (*lrows)[1024] = (unsigned short(*)[1024])shm;   // 16KB
    float* pacc = (float*)(shm + 16384);                            // 12KB [3][4][8][32]
    float* red  = (float*)(shm + 28672);
    int row0 = bid * 8;
    int b = row0 >> 9;
    float4 s4 = ((const float4*)a.ln1)[t];
    for (int j = 0; j < 8; ++j) {
      int row = row0 + j;
      float4 v = ((const float4*)(a.xin + (size_t)row * 1024))[t];
      float ss = v.x * v.x + v.y * v.y + v.z * v.z + v.w * v.w;
      for (int o = 32; o; o >>= 1) ss += __shfl_down(ss, o);
      if ((t & 63) == 0) red[t >> 6] = ss;
      __syncthreads();
      float tot = red[0] + red[1] + red[2] + red[3];
      float rs = rsqrtf(tot * (1.0f / 1024.0f) + 1e-6f);
      ushort4 o;
      o.x = f2bf(v.x * rs * s4.x); o.y = f2bf(v.y * rs * s4.y);
      o.z = f2bf(v.z * rs * s4.z); o.w = f2bf(v.w * rs * s4.w);
      ((ushort4*)(a.xnp + (size_t)row * 1024))[t] = o;
      *(ushort4*)(&lrows[j][t * 4]) = o;
      __syncthreads();
    }
    int r = t & 31, g = t >> 5;
    float acc[3][8];
#pragma unroll
    for (int p = 0; p < 3; ++p)
#pragma unroll
      for (int j = 0; j < 8; ++j) acc[p][j] = 0.f;
    const float* aq = a.qa + (size_t)b * 65536;
    const float* ak = a.ka + (size_t)b * 65536;
    const float* av = a.va + (size_t)b * 65536;
    for (int i = 0; i < 128; ++i) {
      int k = g * 128 + i;
      float a0 = aq[(size_t)k * 32 + r];
      float a1 = ak[(size_t)k * 32 + r];
      float a2 = av[(size_t)k * 32 + r];
#pragma unroll
      for (int j = 0; j < 8; ++j) {
        float xv = bf2f(lrows[j][k]);
        acc[0][j] += xv * a0;
        acc[1][j] += xv * a1;
        acc[2][j] += xv * a2;
      }
    }
    for (int jh = 0; jh < 2; ++jh) {
      __syncthreads();
#pragma unroll
      for (int p = 0; p < 3; ++p)
#pragma unroll
        for (int jj = 0; jj < 4; ++jj)
          pacc[((p * 4 + jj) * 8 + g) * 32 + r] = acc[p][jh * 4 + jj];
      __syncthreads();
      for (int jj = 0; jj < 4; ++jj) {
        int row = row0 + jh * 4 + jj;
        if (t < 96) {
          int p = t >> 5, r2 = t & 31;
          float s = 0.f;
          for (int gg = 0; gg < 8; ++gg) s += pacc[((p * 4 + jj) * 8 + gg) * 32 + r2];
          a.lows[(size_t)row * 128 + p * 32 + r2] = f2bf(s);
        } else if (t < 128) {
          a.lows[(size_t)row * 128 + t] = 0;
        }
      }
    }
    return;
  }
  bid -= 256;
  if (bid < 256) {
    // ---- k_lowc: cross-KV lows (bf16 rows + j-split) ----
    unsigned short* rowsB = (unsigned short*)shm;    // [8][1024] bf16 16KB
    float* pacc = (float*)(shm + 16384);             // 8KB [2][4][8][32]
    int row0 = bid * 8;
    int b = row0 >> 9;
    for (int j = 0; j < 8; ++j) {
      float4 v = ((const float4*)(a.encoded + (size_t)(row0 + j) * 1024))[t];
      ushort4 o;
      o.x = f2bf(v.x); o.y = f2bf(v.y); o.z = f2bf(v.z); o.w = f2bf(v.w);
      *(ushort4*)(rowsB + j * 1024 + t * 4) = o;
    }
    __syncthreads();
    int r = t & 31, g = t >> 5;
    float acc[2][8];
#pragma unroll
    for (int p = 0; p < 2; ++p)
#pragma unroll
      for (int j = 0; j < 8; ++j) acc[p][j] = 0.f;
    const float* a0 = a.lca0 + (size_t)b * 65536;
    const float* a1 = a.lca1 + (size_t)b * 65536;
    for (int i = 0; i < 128; ++i) {
      int k = g * 128 + i;
      float ak = a0[(size_t)k * 32 + r];
      float av = a1[(size_t)k * 32 + r];
#pragma unroll
      for (int j = 0; j < 8; ++j) {
        float x = bf2f(rowsB[j * 1024 + k]);
        acc[0][j] += x * ak;
        acc[1][j] += x * av;
      }
    }
    for (int jh = 0; jh < 2; ++jh) {
      __syncthreads();
#pragma unroll
      for (int p = 0; p < 2; ++p)
#pragma unroll
        for (int jj = 0; jj < 4; ++jj)
          pacc[((p * 4 + jj) * 8 + g) * 32 + r] = acc[p][jh * 4 + jj];
      __syncthreads();
      for (int jj = 0; jj < 4; ++jj) {
        int row = row0 + jh * 4 + jj;
        if (t < 64) {
          int p = t >> 5, r2 = t & 31;
          float s = 0.f;
          for (int gg = 0; gg < 8; ++gg) s += pacc[((p * 4 + jj) * 8 + gg) * 32 + r2];
          a.lowc[(size_t)row * 128 + p * 32 + r2] = f2bf(s);
        } else if (t < 128) {
          a.lowc[(size_t)row * 128 + t] = 0;
        }
      }
    }
    return;
  }
  bid -= 256;
  if (bid < a.nbm) {
    // bmext fill: Bext[b][row=n0+n][c] = (c>>5==sec) ? b_sec[b][c&31][(n0&1023)+n] : 0
    int m = 0;
    while (m < 4 && bid >= a.bmstart[m + 1]) ++m;
    int idx = bid - a.bmstart[m];
    int nrg = a.bmnrg[m];
    int b = idx / nrg, rg = idx % nrg;
    int n0 = rg * 128;
    int sec = n0 >> 10;
    const float* src = a.bmsrc[m][sec] + (size_t)b * 65536;
    unsigned short* dst = a.bmdst[m] + ((size_t)b * nrg * 128 + n0) * 128;
    int n = t & 127, coff = (t >> 7) * 64;
    int ncol = (n0 & 1023) + n;
    unsigned short* drow = dst + (size_t)n * 128 + coff;
    for (int cg = 0; cg < 16; cg += 8) {
      float vv[8][4];
#pragma unroll
      for (int cc = 0; cc < 8; ++cc)
#pragma unroll
        for (int e = 0; e < 4; ++e) {
          int c = coff + (cg + cc) * 4 + e;
          vv[cc][e] = ((c >> 5) == sec) ? src[(size_t)(c & 31) * 1024 + ncol] : 0.f;
        }
#pragma unroll
      for (int cc = 0; cc < 8; ++cc) {
        ushort4 o;
        o.x = f2bf(vv[cc][0]); o.y = f2bf(vv[cc][1]);
        o.z = f2bf(vv[cc][2]); o.w = f2bf(vv[cc][3]);
        *(ushort4*)(drow + (cg + cc) * 4) = o;
      }
    }
    return;
  }
  bid -= a.nbm;
  if (bid < 32) {
    int i = bid * 256 + t;
    if (i < 16 * 512) {
      int h = i >> 9, d = i & 511;
      int bucket;
      if (d < 16) bucket = d;
      else {
        int lb = 16 + (int)(logf((float)d / 16.0f) / logf(8.0f) * 16.0f);
        bucket = lb < 31 ? lb : 31;
      }
      a.rb[i] = a.table[bucket * 16 + h];
    }
    return;
  }
  bid -= 32;
  if (bid < a.nf2bf) {
    // 256 blocks x 8 batched float4 per thread (2M floats total).
    const float4* src = (const float4*)a.encoded;
    ushort4* dst = (ushort4*)a.encbf;
    int base = bid * 2048 + t;
    float4 v[8];
#pragma unroll
    for (int i = 0; i < 8; ++i) v[i] = src[base + i * 256];
#pragma unroll
    for (int i = 0; i < 8; ++i) {
      ushort4 o;
      o.x = f2bf(v[i].x); o.y = f2bf(v[i].y); o.z = f2bf(v[i].z); o.w = f2bf(v[i].w);
      dst[base + i * 256] = o;
    }
    return;
  }
  bid -= a.nf2bf;
  {
    // early weight transposes (q,k,v,ck,cv): 128x128 tiles
    int z = 0;
    while (z < 4 && bid >= a.tstart[z + 1]) ++z;
    int tile = bid - a.tstart[z];
    transpose_tile128(a.src[z], a.dst[z], 1024, 1024, 0,
                      tile & 7, tile >> 3, shm, t);
  }
}

// ---------------- k_addbrms: 4-partial sum + resid + rms (+ next low) -----
template<bool LOW>
__global__ __launch_bounds__(256) void k_addbrms(const float* parts, const float* resid,
                                                 const float* sc, float* resout,
                                                 unsigned short* xn,
                                                 const float* aP, unsigned short* lowext) {
  __shared__ unsigned short lrows[8][1024];
  __shared__ float pacc[8 * 8 * 32];
  __shared__ float red[4];
  const size_t PART = (size_t)2048 * 1024;
  int t = threadIdx.x;
  int row0 = blockIdx.x * 8;
  int b = row0 >> 9;
  float4 s4 = ((const float4*)sc)[t];
  for (int j = 0; j < 8; ++j) {
    int row = row0 + j;
    const float* p0 = parts + (size_t)row * 1024;
    float4 v = ((const float4*)p0)[t];
    float4 v1 = ((const float4*)(p0 + PART))[t];
    float4 v2 = ((const float4*)(p0 + 2 * PART))[t];
    float4 v3 = ((const float4*)(p0 + 3 * PART))[t];
    float4 rv = ((const float4*)(resid + (size_t)row * 1024))[t];
    float4 s;
    s.x = v.x + v1.x + v2.x + v3.x + rv.x;
    s.y = v.y + v1.y + v2.y + v3.y + rv.y;
    s.z = v.z + v1.z + v2.z + v3.z + rv.z;
    s.w = v.w + v1.w + v2.w + v3.w + rv.w;
    ((float4*)(resout + (size_t)row * 1024))[t] = s;
    float ss = s.x * s.x + s.y * s.y + s.z * s.z + s.w * s.w;
    for (int o = 32; o; o >>= 1) ss += __shfl_down(ss, o);
    if ((t & 63) == 0) red[t >> 6] = ss;
    __syncthreads();
    float tot = red[0] + red[1] + red[2] + red[3];
    float rs = rsqrtf(tot * (1.0f / 1024.0f) + 1e-6f);
    ushort4 o;
    o.x = f2bf(s.x * rs * s4.x); o.y = f2bf(s.y * rs * s4.y);
    o.z = f2bf(s.z * rs * s4.z); o.w = f2bf(s.w * rs * s4.w);
    ((ushort4*)(xn + (size_t)row * 1024))[t] = o;
    if (LOW) *(ushort4*)(&lrows[j][t * 4]) = o;
    __syncthreads();
  }
  if (LOW) {
    int r = t & 31, g = t >> 5;
    float acc[8];
#pragma unroll
    for (int j = 0; j < 8; ++j) acc[j] = 0.f;
    const float* ap = aP + (size_t)b * 65536;
    for (int i = 0; i < 128; ++i) {
      int k = g * 128 + i;
      float a0 = ap[(size_t)k * 32 + r];
#pragma unroll
      for (int j = 0; j < 8; ++j) acc[j] += bf2f(lrows[j][k]) * a0;
    }
#pragma unroll
    for (int j = 0; j < 8; ++j) pacc[(j * 8 + g) * 32 + r] = acc[j];
    __syncthreads();
    for (int j = 0; j < 8; ++j) {
      if (t < 32) {
        float s = 0.f;
        for (int gg = 0; gg < 8; ++gg) s += pacc[(j * 8 + gg) * 32 + t];
        lowext[(size_t)(row0 + j) * 128 + t] = f2bf(s);
      } else if (t < 128) {
        lowext[(size_t)(row0 + j) * 128 + t] = 0;
      }
    }
  }
}

// ---------------- low for out-proj (ctx bf16 -> lowext bf16) --------------
__global__ __launch_bounds__(256) void k_lowbf(const unsigned short* x, const float* a,
                                               unsigned short* lowext) {
  int row0 = blockIdx.x * 8;
  int b = row0 >> 9;
  int t = threadIdx.x, r = t & 31, j = t >> 5;
  int row = row0 + j;
  const bf16x8* xv = (const bf16x8*)(x + (size_t)row * 1024);
  const float* ap = a + (size_t)b * 65536;
  float s = 0.f;
  for (int kb = 0; kb < 128; ++kb) {
    bf16x8 v = xv[kb];
#pragma unroll
    for (int u = 0; u < 8; ++u)
      s += (float)v[u] * ap[(size_t)(kb * 8 + u) * 32 + r];
  }
  lowext[(size_t)row * 128 + r] = f2bf(s);
  lowext[(size_t)row * 128 + 32 + r] = 0;
  lowext[(size_t)row * 128 + 64 + r] = 0;
  lowext[(size_t)row * 128 + 96 + r] = 0;
}

// ---------------- final sum ----------------
__global__ void k_sum4(const float* p, size_t pstride, const float* resid, float* out) {
  int i = blockIdx.x * 256 + threadIdx.x;
  float4 a = ((const float4*)p)[i];
  float4 b = ((const float4*)(p + pstride))[i];
  float4 c = ((const float4*)(p + 2 * pstride))[i];
  float4 d = ((const float4*)(p + 3 * pstride))[i];
  float4 r = ((const float4*)resid)[i];
  float4 o;
  o.x = a.x + b.x + c.x + d.x + r.x;
  o.y = a.y + b.y + c.y + d.y + r.y;
  o.z = a.z + b.z + c.z + d.z + r.z;
  o.w = a.w + b.w + c.w + d.w + r.w;
  ((float4*)out)[i] = o;
}

// ---------------------------------------------------------------------------

extern "C" void kernel_launch(void* const* d_in, const int* in_sizes, int n_in,
                              void* d_out, int out_size, void* d_ws, size_t ws_size,
                              hipStream_t stream) {
  const float* f_inputs  = (const float*)d_in[0];
  const float* f_encoded = (const float*)d_in[1];
  const float* f_qa = (const float*)d_in[2];
  const float* f_qb = (const float*)d_in[3];
  const float* f_ka = (const float*)d_in[4];
  const float* f_kb = (const float*)d_in[5];
  const float* f_va = (const float*)d_in[6];
  const float* f_vb = (const float*)d_in[7];
  const float* f_oa = (const float*)d_in[8];
  const float* f_ob = (const float*)d_in[9];
  const float* f_table = (const float*)d_in[10];
  const float* f_ln1 = (const float*)d_in[11];
  const float* f_ln2 = (const float*)d_in[12];
  const float* f_ln3 = (const float*)d_in[13];
  const float* f_W[8] = { (const float*)d_in[14], (const float*)d_in[15],
                          (const float*)d_in[16], (const float*)d_in[17],
                          (const float*)d_in[18], (const float*)d_in[19],
                          (const float*)d_in[20], (const float*)d_in[21] };
  const float* f_wi0 = (const float*)d_in[22];
  const float* f_wi1 = (const float*)d_in[23];
  const float* f_wo  = (const float*)d_in[24];

  const size_t SEL1 = 32768;
  const size_t PART = (size_t)2048 * 1024;

  char* w = (char*)d_ws;
  size_t off = 0;
  auto alloc = [&](size_t bytes) -> char* {
    off = (off + 255) & ~(size_t)255;
    char* p = w + off;
    off += bytes;
    return p;
  };
  unsigned short* wt  = (unsigned short*)alloc((size_t)8192 * 1024 * 2); // q,k,v,o,cq,ck,cv,co
  unsigned short* wc  = (unsigned short*)alloc((size_t)8192 * 1024 * 2); // interleaved wi0/wi1
  unsigned short* wot = (unsigned short*)alloc((size_t)1024 * 4096 * 2);
  unsigned short* encbf = (unsigned short*)alloc(2048 * 1024 * 2);
  float* rb = (float*)alloc(16 * 512 * 4);
  unsigned short* xn  = (unsigned short*)alloc(2048 * 1024 * 2);
  unsigned short* qbf = (unsigned short*)alloc(2048 * 1024 * 2);
  unsigned short* kbf = (unsigned short*)alloc(2048 * 1024 * 2);
  unsigned short* vtb = (unsigned short*)alloc((size_t)64 * 64 * 512 * 2);
  unsigned short* kbf2 = (unsigned short*)alloc(2048 * 1024 * 2);
  unsigned short* vtb2 = (unsigned short*)alloc((size_t)64 * 64 * 512 * 2);
  unsigned short* lowext_s = (unsigned short*)alloc(2048 * 128 * 2);
  unsigned short* lowext_c = (unsigned short*)alloc(2048 * 128 * 2);
  unsigned short* lowext_q = (unsigned short*)alloc(2048 * 128 * 2);
  unsigned short* lowext_o = (unsigned short*)alloc(2048 * 128 * 2);
  unsigned short* bmext_s  = (unsigned short*)alloc((size_t)4 * 3072 * 128 * 2);
  unsigned short* bmext_c  = (unsigned short*)alloc((size_t)4 * 2048 * 128 * 2);
  unsigned short* bmext_q  = (unsigned short*)alloc((size_t)4 * 1024 * 128 * 2);
  unsigned short* bmext_o  = (unsigned short*)alloc((size_t)4 * 1024 * 128 * 2);
  unsigned short* bmext_o2 = (unsigned short*)alloc((size_t)4 * 1024 * 128 * 2);
  unsigned short* ctxb = (unsigned short*)alloc(2048 * 1024 * 2);
  float* xres = (float*)alloc(2048 * 1024 * 4);
  float* yres = (float*)alloc(2048 * 1024 * 4);
  char*  big  = alloc((size_t)84 << 20);
  // big aliases (stream-serial lifetimes):
  float* op_s = (float*)big;                           // self out-proj partials 4x8 MB
  float* qp_c = (float*)(big + ((size_t)32 << 20));    // cross-Q partials 4x8 MB
  float* op_c = (float*)big;                           // cross out-proj partials 4x8 MB
  unsigned short* hbf = (unsigned short*)big;          // 16 MB
  float* fp   = (float*)(big + ((size_t)16 << 20));    // final partials 4x8 MB
  (void)ws_size; (void)in_sizes; (void)n_in; (void)out_size;

  // ---- mega prep (early transposes: q,k,v slots 0,1,2; ck,cv slots 5,6) --
  PrepArgs pa;
  {
    const float* wsrc5[5] = { f_W[0], f_W[1], f_W[2], f_W[5], f_W[6] };
    const int slot5[5] = { 0, 1, 2, 5, 6 };
    int ts = 0;
    for (int i = 0; i < 5; ++i) {
      pa.src[i] = wsrc5[i];
      pa.dst[i] = wt + (size_t)slot5[i] * 1024 * 1024;
      pa.tstart[i] = ts; ts += 64;                    // (1024/128)^2
    }
    pa.tstart[5] = ts;
    pa.nwt = ts;                                      // 320
  }
  pa.encoded = f_encoded; pa.encbf = encbf;
  pa.table = f_table; pa.rb = rb;
  pa.nf2bf = 256;
  pa.bmdst[0] = bmext_s;  pa.bmnrg[0] = 24;
  pa.bmsrc[0][0] = f_qb; pa.bmsrc[0][1] = f_kb; pa.bmsrc[0][2] = f_vb;
  pa.bmdst[1] = bmext_c;  pa.bmnrg[1] = 16;
  pa.bmsrc[1][0] = f_kb + SEL1; pa.bmsrc[1][1] = f_vb + SEL1; pa.bmsrc[1][2] = nullptr;
  pa.bmdst[2] = bmext_q;  pa.bmnrg[2] = 8;
  pa.bmsrc[2][0] = f_qb + SEL1; pa.bmsrc[2][1] = nullptr; pa.bmsrc[2][2] = nullptr;
  pa.bmdst[3] = bmext_o;  pa.bmnrg[3] = 8;
  pa.bmsrc[3][0] = f_ob; pa.bmsrc[3][1] = nullptr; pa.bmsrc[3][2] = nullptr;
  pa.bmdst[4] = bmext_o2; pa.bmnrg[4] = 8;
  pa.bmsrc[4][0] = f_ob + SEL1; pa.bmsrc[4][1] = nullptr; pa.bmsrc[4][2] = nullptr;
  int bs = 0;
  for (int m = 0; m < 5; ++m) { pa.bmstart[m] = bs; bs += pa.bmnrg[m] * 4; }
  pa.bmstart[5] = bs;
  pa.nbm = bs;
  pa.xin = f_inputs; pa.ln1 = f_ln1;
  pa.qa = f_qa; pa.ka = f_ka; pa.va = f_va;
  pa.xnp = xn; pa.lows = lowext_s;
  pa.lca0 = f_ka + SEL1; pa.lca1 = f_va + SEL1;
  pa.lowc = lowext_c;
  int totblk = 512 + pa.nbm + 32 + pa.nf2bf + pa.nwt;
  k_prep<<<dim3(totblk), dim3(256), 0, stream>>>(pa);

  // ---- big QKV fused + late transposes (Wo,cWq,cWo,wi0,wi1,wo) ----
  {
    QKVT g;
    g.s[0] = { xn, lowext_s, wt, bmext_s,
               qbf, kbf, vtb, (size_t)3072 * 128, 2, 24 };
    g.s[1] = { encbf, lowext_c, wt + (size_t)5120 * 1024, bmext_c,
               kbf2, vtb2, nullptr, (size_t)2048 * 128, 1, 16 };
    const float* tsrc[6] = { f_W[3], f_W[4], f_W[7], f_wi0, f_wi1, f_wo };
    unsigned short* tdst[6] = { wt + (size_t)3072 * 1024, wt + (size_t)4096 * 1024,
                                wt + (size_t)7168 * 1024, wc, wc, wot };
    int tK[6] = { 1024, 1024, 1024, 1024, 1024, 4096 };
    int tN[6] = { 1024, 1024, 1024, 4096, 4096, 1024 };
    int tmode[6] = { 0, 0, 0, 1, 2, 0 };
    int ts2 = 0;
    for (int i = 0; i < 6; ++i) {
      g.tsrc[i] = tsrc[i]; g.tdst[i] = tdst[i];
      g.tK[i] = tK[i]; g.tN[i] = tN[i]; g.tmode[i] = tmode[i];
      g.tstart[i] = ts2;
      ts2 += (tK[i] >> 7) * (tN[i] >> 7);             // 64 or 256 tiles
    }
    g.tstart[6] = ts2;
    g.ntt = ts2;                                      // 960
    k_gemmqkv<<<dim3(24, 16, 5), dim3(256), 0, stream>>>(g);
  }

  k_flash<true, false><<<dim3(8, 64), dim3(256), 0, stream>>>(qbf, nullptr, kbf, vtb, rb, ctxb);

  // ---- self out-proj (K-ext lora_o, S4) ----
  k_lowbf<<<dim3(256), dim3(256), 0, stream>>>(ctxb, f_oa, lowext_o);
  {
    GX g;
    for (int s = 0; s < 4; ++s)
      g.s[s] = { ctxb, lowext_o, wt + (size_t)3072 * 1024, bmext_o, op_s + (size_t)s * PART,
                 (size_t)1024 * 128, 1024, 8, s * 18 / 4, (s + 1) * 18 / 4 };
    k_gemmx<<<dim3(8, 16, 4), dim3(256), 0, stream>>>(g);
  }
  k_addbrms<true><<<dim3(256), dim3(256), 0, stream>>>(op_s, f_inputs, f_ln2, xres, xn,
                                                       f_qa + SEL1, lowext_q);

  // ---- cross-Q (K-ext, S4) ----
  {
    GX g;
    for (int s = 0; s < 4; ++s)
      g.s[s] = { xn, lowext_q, wt + (size_t)4096 * 1024, bmext_q, qp_c + (size_t)s * PART,
                 (size_t)1024 * 128, 1024, 8, s * 18 / 4, (s + 1) * 18 / 4 };
    k_gemmx<<<dim3(8, 16, 4), dim3(256), 0, stream>>>(g);
  }
  k_flash<false, true><<<dim3(8, 64), dim3(256), 0, stream>>>(nullptr, qp_c, kbf2, vtb2, rb, ctxb);

  // ---- cross out-proj (K-ext lora_o sel1, S4) ----
  k_lowbf<<<dim3(256), dim3(256), 0, stream>>>(ctxb, f_oa + SEL1, lowext_o);
  {
    GX g;
    for (int s = 0; s < 4; ++s)
      g.s[s] = { ctxb, lowext_o, wt + (size_t)7168 * 1024, bmext_o2, op_c + (size_t)s * PART,
                 (size_t)1024 * 128, 1024, 8, s * 18 / 4, (s + 1) * 18 / 4 };
    k_gemmx<<<dim3(8, 16, 4), dim3(256), 0, stream>>>(g);
  }
  k_addbrms<false><<<dim3(256), dim3(256), 0, stream>>>(op_c, xres, f_ln3, yres, xn,
                                                        nullptr, nullptr);

  // ---- MLP ----
  k_mlp<<<dim3(32, 16), dim3(512), 0, stream>>>(xn, wc, hbf);
  k_gemm1s<<<dim3(8, 16, 4), dim3(256), 0, stream>>>(hbf, wot, fp, PART, 1024, 4096, 4096, 1024);
  k_sum4<<<dim3(2048), dim3(256), 0, stream>>>(fp, PART, yres, (float*)d_out);
}